// Round 10
// baseline (797.941 us; speedup 1.0000x reference)
//
#include <hip/hip_runtime.h>
#include <hip/hip_cooperative_groups.h>

namespace cg = cooperative_groups;

#define NN 50000
#define CAP 32          // per-node bin capacity; overflow handled correctly
#define OVF_CAP 4096
#define SHARD_W 64      // 64-node shards; one bin phase block OWNS a shard
#define NSH 782         // ceil(50000/64)
#define NPB 512         // partition blocks per relation (R6-proven)

__device__ __forceinline__ unsigned short f2bf(float f) {
    unsigned u = __float_as_uint(f);
    u += 0x7fffu + ((u >> 16) & 1u);           // round-to-nearest-even
    return (unsigned short)(u >> 16);
}
__device__ __forceinline__ float bf2f(unsigned short u) {
    return __uint_as_float(((unsigned)u) << 16);
}

// ---- R21: the 7 binning launches fused into ONE cooperative kernel ----
// R9 lesson: all kernels below the 45us fills; floors sum ~90us vs 245
// measured => launch boundaries (~3-6us x 11) are a top remaining cost.
// Phase code is byte-identical to R6's proven kernels; launches become
// grid.sync()s. LDS: one 6.3KB buffer aliased per phase. Grid 1024 blocks
// (= 2*NPB) is well under co-residency limit (6.3KB LDS, low VGPR).
__global__ __launch_bounds__(256) void binning_coop(
    const float* __restrict__ x, unsigned short* __restrict__ xb,
    const int* __restrict__ ei0, int E0,
    const int* __restrict__ ei1, int E1,
    unsigned short* __restrict__ hist16,        // [2][NSH][NPB] (aliases aggb)
    int* __restrict__ tot, int* __restrict__ sbase,
    unsigned* __restrict__ pbase,               // [2][NSH][NPB]
    unsigned* __restrict__ compact,             // [E0+E1] u32 (aliases h1b)
    unsigned short* __restrict__ bins, int* __restrict__ deg,
    int2* __restrict__ ovf, int* __restrict__ ovf_cnt)
{
    cg::grid_group grid = cg::this_grid();
    __shared__ unsigned sh[2 * NSH];            // 6.3KB, aliased per phase
    int tid  = threadIdx.x;
    int gtid = blockIdx.x * 256 + tid;
    int gsz  = gridDim.x * 256;

    // P0: x -> bf16 convert + zero ovf_cnt (independent of P1 — no sync).
    for (int i = gtid; i < NN * 16; i += gsz) {
        float4 v = ((const float4*)x)[i];
        ushort4 o;
        o.x = f2bf(v.x); o.y = f2bf(v.y); o.z = f2bf(v.z); o.w = f2bf(v.w);
        ((ushort4*)xb)[i] = o;
    }
    if (gtid < 8) ovf_cnt[gtid] = 0;

    // P1: shard_hist (block mapping identical to R6).
    {
        unsigned* lh = sh;
        int local = blockIdx.x; int rel = 0;
        if (local >= NPB) { local -= NPB; rel = 1; }
        int pb = (local & 7) * (NPB / 8) + (local >> 3);
        const int* ei = rel ? ei1 : ei0;
        int E         = rel ? E1  : E0;
        int ce = (E + NPB - 1) / NPB;
        int lo = pb * ce, hi = min(lo + ce, E);
        for (int i = tid; i < NSH; i += 256) lh[i] = 0;
        __syncthreads();
        for (int t = lo + tid; t < hi; t += 256)
            atomicAdd(&lh[ei[E + t] >> 6], 1u);
        __syncthreads();
        for (int i = tid; i < NSH; i += 256)
            hist16[((size_t)rel * NSH + i) * NPB + pb] = (unsigned short)lh[i];
    }
    grid.sync();

    // P2: total — one wave per (rel,shard), coalesced row reduce.
    {
        int gw = gtid >> 6;
        int lane = tid & 63;
        if (gw < 2 * NSH) {
            uint4 v = ((const uint4*)(hist16 + (size_t)gw * NPB))[lane];
            unsigned s = (v.x & 0xffffu) + (v.x >> 16) + (v.y & 0xffffu) + (v.y >> 16)
                       + (v.z & 0xffffu) + (v.z >> 16) + (v.w & 0xffffu) + (v.w >> 16);
            for (int off = 32; off; off >>= 1) s += __shfl_down(s, off);
            if (lane == 0) tot[gw] = (int)s;
        }
    }
    grid.sync();

    // P3: exclusive scan of 1564 totals (block 0 only).
    if (blockIdx.x == 0) {
        int* ps = (int*)sh;
        int t = tid;
        int v[7];
        int s = 0;
        #pragma unroll
        for (int j = 0; j < 7; j++) {
            int i = t * 7 + j;
            v[j] = (i < 2 * NSH) ? tot[i] : 0;
            s += v[j];
        }
        ps[t] = s;
        __syncthreads();
        for (int off = 1; off < 256; off <<= 1) {
            int add = (t >= off) ? ps[t - off] : 0;
            __syncthreads();
            ps[t] += add;
            __syncthreads();
        }
        int run = (t == 0) ? 0 : ps[t - 1];
        #pragma unroll
        for (int j = 0; j < 7; j++) {
            int i = t * 7 + j;
            if (i < 2 * NSH) sbase[i] = run;
            run += v[j];
        }
        if (t == 255) sbase[2 * NSH] = run;
    }
    grid.sync();

    // P4: blockbase — lane-local prefix + shfl_up wave scan.
    {
        int gw = gtid >> 6;
        int lane = tid & 63;
        if (gw < 2 * NSH) {
            uint4 v = ((const uint4*)(hist16 + (size_t)gw * NPB))[lane];
            unsigned c[8] = {v.x & 0xffffu, v.x >> 16, v.y & 0xffffu, v.y >> 16,
                             v.z & 0xffffu, v.z >> 16, v.w & 0xffffu, v.w >> 16};
            unsigned lsum = 0;
            #pragma unroll
            for (int j = 0; j < 8; j++) lsum += c[j];
            unsigned incl = lsum;
            for (int off = 1; off < 64; off <<= 1) {
                unsigned n = __shfl_up(incl, off);
                if (lane >= off) incl += n;
            }
            unsigned run = (unsigned)sbase[gw] + incl - lsum;
            unsigned* prow = pbase + (size_t)gw * NPB + lane * 8;
            #pragma unroll
            for (int j = 0; j < 8; j++) { prow[j] = run; run += c[j]; }
        }
    }
    grid.sync();

    // P5: partition — scatter edges into shard-segregated compact array.
    {
        unsigned* lbase = sh;
        unsigned* lrank = sh + NSH;
        int local = blockIdx.x; int rel = 0;
        if (local >= NPB) { local -= NPB; rel = 1; }
        int pb = (local & 7) * (NPB / 8) + (local >> 3);
        const int* ei = rel ? ei1 : ei0;
        int E         = rel ? E1  : E0;
        int ce = (E + NPB - 1) / NPB;
        int lo = pb * ce, hi = min(lo + ce, E);
        __syncthreads();    // sh reuse: P3/P4 done grid-wide; block-local reuse safe
        for (int i = tid; i < NSH; i += 256) {
            lbase[i] = pbase[((size_t)rel * NSH + i) * NPB + pb];
            lrank[i] = 0;
        }
        __syncthreads();
        for (int t = lo + tid; t < hi; t += 256) {
            int dst = ei[E + t];
            int src = ei[t];
            int s = dst >> 6;
            unsigned r = atomicAdd(&lrank[s], 1u);
            compact[lbase[s] + r] = ((unsigned)dst << 16) | (unsigned)src;
        }
    }
    grid.sync();

    // P6: bin — grid-stride over 1564 (rel,shard) blocks.
    {
        unsigned* lcnt = sh;
        for (int bid = blockIdx.x; bid < 2 * NSH; bid += gridDim.x) {
            if (tid < SHARD_W) lcnt[tid] = 0;
            __syncthreads();
            int rel = bid / NSH;
            int s   = bid - rel * NSH;
            int base = sbase[bid];
            int tt   = sbase[bid + 1] - base;
            int taskbase = rel * NN + s * SHARD_W;
            for (int j = tid; j < tt; j += 256) {
                unsigned e = compact[base + j];
                int dst = (int)(e >> 16);
                int src = (int)(e & 0xffffu);
                int loc = dst & (SHARD_W - 1);
                unsigned r = atomicAdd(&lcnt[loc], 1u);
                int task = taskbase + loc;
                if (r < CAP) {
                    bins[(size_t)task * CAP + r] = (unsigned short)src;
                } else {
                    int o = atomicAdd(ovf_cnt, 1);
                    if (o < OVF_CAP) ovf[o] = make_int2(task, src);
                }
            }
            __syncthreads();
            if (tid < SHARD_W) {
                int node = s * SHARD_W + tid;
                if (node < NN) deg[rel * NN + node] = (int)lcnt[tid];
            }
            __syncthreads();
        }
    }
}

// One (rel,node) task per wave; paired bf16 gathers; inline overflow pickup.
__global__ __launch_bounds__(256) void aggregate(
    const unsigned short* __restrict__ bins, const int* __restrict__ deg,
    const unsigned short* __restrict__ hb, unsigned short* __restrict__ agg,
    const int2* __restrict__ ovf, const int* __restrict__ ovf_cnt)
{
    int lane = threadIdx.x & 63;
    int half = lane >> 5;
    int p = lane & 31;                 // feature-pair index
    int wid = (blockIdx.x * blockDim.x + threadIdx.x) >> 6;
    int nwaves = (gridDim.x * blockDim.x) >> 6;
    const unsigned int* hb32 = (const unsigned int*)hb;
    unsigned int* agg32 = (unsigned int*)agg;

    for (int task = wid; task < 2 * NN; task += nwaves) {
        int d = deg[task];
        int m = min(d, CAP);
        int idx = 0;
        if (lane < m) idx = bins[(size_t)task * CAP + lane];
        float a00=0.f,a01=0.f, a10=0.f,a11=0.f, a20=0.f,a21=0.f, a30=0.f,a31=0.f;
        int F = m >> 1;                // complete pair-steps
        int q = 0;
        for (; q + 4 <= F; q += 4) {
            int s0 = __shfl(idx, 2*(q+0) + half);
            int s1 = __shfl(idx, 2*(q+1) + half);
            int s2 = __shfl(idx, 2*(q+2) + half);
            int s3 = __shfl(idx, 2*(q+3) + half);
            unsigned u0 = hb32[(size_t)s0 * 32 + p];
            unsigned u1 = hb32[(size_t)s1 * 32 + p];
            unsigned u2 = hb32[(size_t)s2 * 32 + p];
            unsigned u3 = hb32[(size_t)s3 * 32 + p];
            a00 += __uint_as_float(u0 << 16); a01 += __uint_as_float(u0 & 0xffff0000u);
            a10 += __uint_as_float(u1 << 16); a11 += __uint_as_float(u1 & 0xffff0000u);
            a20 += __uint_as_float(u2 << 16); a21 += __uint_as_float(u2 & 0xffff0000u);
            a30 += __uint_as_float(u3 << 16); a31 += __uint_as_float(u3 & 0xffff0000u);
        }
        for (; q < F; ++q) {
            int s = __shfl(idx, 2*q + half);
            unsigned u = hb32[(size_t)s * 32 + p];
            a00 += __uint_as_float(u << 16); a01 += __uint_as_float(u & 0xffff0000u);
        }
        if (m & 1) {
            int s = __shfl(idx, m - 1);
            if (half == 0) {
                unsigned u = hb32[(size_t)s * 32 + p];
                a00 += __uint_as_float(u << 16); a01 += __uint_as_float(u & 0xffff0000u);
            }
        }
        if (d > CAP) {                 // rare: pick up this task's overflow edges
            int cnt = min(*ovf_cnt, OVF_CAP);
            for (int e = 0; e < cnt; ++e) {
                int2 v = ovf[e];
                if (v.x == task && half == 0) {
                    unsigned u = hb32[(size_t)v.y * 32 + p];
                    a00 += __uint_as_float(u << 16); a01 += __uint_as_float(u & 0xffff0000u);
                }
            }
        }
        float s0 = (a00 + a10) + (a20 + a30);
        float s1 = (a01 + a11) + (a21 + a31);
        s0 += __shfl_xor(s0, 32);
        s1 += __shfl_xor(s1, 32);
        if (half == 0) {
            float inv = 1.0f / (float)max(d, 1);
            unsigned lo = (unsigned)f2bf(s0 * inv);
            unsigned hi = (unsigned)f2bf(s1 * inv);
            agg32[(size_t)task * 32 + p] = lo | (hi << 16);
        }
    }
}

// 64-node-tile GEMMs (R20; neutral vs 128-tile, kept for lower LDS).
#define RST 66
__global__ __launch_bounds__(256) void layer_gemm(
    const unsigned short* __restrict__ agg0, const unsigned short* __restrict__ agg1,
    const unsigned short* __restrict__ selfb,
    const float* __restrict__ Wl0, const float* __restrict__ Wl1,
    const float* __restrict__ Wr0, const float* __restrict__ Wr1,
    const float* __restrict__ b0, const float* __restrict__ b1,
    unsigned short* __restrict__ hb16)
{
    __shared__ float Wch[64 * 64];
    __shared__ float rowsT[64 * RST];
    __shared__ float bias[64];

    int tid = threadIdx.x;
    int base = blockIdx.x * 64;
    if (tid < 64) bias[tid] = b0[tid] + b1[tid];

    int j8 = (tid & 7) * 8;
    int n2 = (tid >> 3) * 2;

    float acc[2][8];
    #pragma unroll
    for (int i = 0; i < 2; i++)
        #pragma unroll
        for (int c = 0; c < 8; c++) acc[i][c] = 0.f;

    for (int chunk = 0; chunk < 3; chunk++) {
        const float* W = (chunk == 0) ? Wl0 : (chunk == 1) ? Wl1 : Wr0;
        const unsigned short* src = (chunk == 0) ? agg0 : (chunk == 1) ? agg1 : selfb;
        __syncthreads();
        #pragma unroll
        for (int r = 0; r < 4; r++) {
            int i = tid + 256 * r;
            float4 w = *(const float4*)&W[i * 4];
            if (chunk == 2) {
                float4 w2 = *(const float4*)&Wr1[i * 4];
                w.x += w2.x; w.y += w2.y; w.z += w2.z; w.w += w2.w;
            }
            *(float4*)&Wch[i * 4] = w;
        }
        #pragma unroll
        for (int r = 0; r < 4; r++) {       // 64 nodes x 16 k4-groups = 1024
            int i = tid + 256 * r;
            int node = i >> 4;
            int k4 = (i & 15) * 4;
            int g = base + node;
            ushort4 u = make_ushort4(0, 0, 0, 0);
            if (g < NN) u = *(const ushort4*)&src[(size_t)g * 64 + k4];
            rowsT[(k4 + 0) * RST + node] = bf2f(u.x);
            rowsT[(k4 + 1) * RST + node] = bf2f(u.y);
            rowsT[(k4 + 2) * RST + node] = bf2f(u.z);
            rowsT[(k4 + 3) * RST + node] = bf2f(u.w);
        }
        __syncthreads();
        #pragma unroll 4
        for (int k = 0; k < 64; k++) {
            float4 wa = *(const float4*)&Wch[k * 64 + j8];
            float4 wb = *(const float4*)&Wch[k * 64 + j8 + 4];
            float2 rv = *(const float2*)&rowsT[k * RST + n2];
            float w[8] = {wa.x, wa.y, wa.z, wa.w, wb.x, wb.y, wb.z, wb.w};
            float rr[2] = {rv.x, rv.y};
            #pragma unroll
            for (int i = 0; i < 2; i++)
                #pragma unroll
                for (int c = 0; c < 8; c++)
                    acc[i][c] = fmaf(rr[i], w[c], acc[i][c]);
        }
    }

    #pragma unroll
    for (int i = 0; i < 2; i++) {
        int g = base + n2 + i;
        if (g < NN) {
            ushort4 p0, p1;
            p0.x = f2bf(fmaxf(acc[i][0] + bias[j8 + 0], 0.f));
            p0.y = f2bf(fmaxf(acc[i][1] + bias[j8 + 1], 0.f));
            p0.z = f2bf(fmaxf(acc[i][2] + bias[j8 + 2], 0.f));
            p0.w = f2bf(fmaxf(acc[i][3] + bias[j8 + 3], 0.f));
            p1.x = f2bf(fmaxf(acc[i][4] + bias[j8 + 4], 0.f));
            p1.y = f2bf(fmaxf(acc[i][5] + bias[j8 + 5], 0.f));
            p1.z = f2bf(fmaxf(acc[i][6] + bias[j8 + 6], 0.f));
            p1.w = f2bf(fmaxf(acc[i][7] + bias[j8 + 7], 0.f));
            *(ushort4*)&hb16[(size_t)g * 64 + j8]     = p0;
            *(ushort4*)&hb16[(size_t)g * 64 + j8 + 4] = p1;
        }
    }
}

// L1 + final fused (64-node tile): h2 tile in LDS, then out = h2 @ linW + linb.
__global__ __launch_bounds__(256) void layer_gemm_final(
    const unsigned short* __restrict__ agg0, const unsigned short* __restrict__ agg1,
    const unsigned short* __restrict__ selfb,
    const float* __restrict__ Wl0, const float* __restrict__ Wl1,
    const float* __restrict__ Wr0, const float* __restrict__ Wr1,
    const float* __restrict__ b0, const float* __restrict__ b1,
    const float* __restrict__ linW, const float* __restrict__ linb,
    float* __restrict__ out)
{
    __shared__ float Wch[64 * 64];
    __shared__ float rowsT[64 * RST];
    __shared__ float bias[64];

    int tid = threadIdx.x;
    int base = blockIdx.x * 64;
    if (tid < 64) bias[tid] = b0[tid] + b1[tid];

    int j8 = (tid & 7) * 8;
    int n2 = (tid >> 3) * 2;

    float acc[2][8];
    #pragma unroll
    for (int i = 0; i < 2; i++)
        #pragma unroll
        for (int c = 0; c < 8; c++) acc[i][c] = 0.f;

    for (int chunk = 0; chunk < 3; chunk++) {
        const float* W = (chunk == 0) ? Wl0 : (chunk == 1) ? Wl1 : Wr0;
        const unsigned short* src = (chunk == 0) ? agg0 : (chunk == 1) ? agg1 : selfb;
        __syncthreads();
        #pragma unroll
        for (int r = 0; r < 4; r++) {
            int i = tid + 256 * r;
            float4 w = *(const float4*)&W[i * 4];
            if (chunk == 2) {
                float4 w2 = *(const float4*)&Wr1[i * 4];
                w.x += w2.x; w.y += w2.y; w.z += w2.z; w.w += w2.w;
            }
            *(float4*)&Wch[i * 4] = w;
        }
        #pragma unroll
        for (int r = 0; r < 4; r++) {
            int i = tid + 256 * r;
            int node = i >> 4;
            int k4 = (i & 15) * 4;
            int g = base + node;
            ushort4 u = make_ushort4(0, 0, 0, 0);
            if (g < NN) u = *(const ushort4*)&src[(size_t)g * 64 + k4];
            rowsT[(k4 + 0) * RST + node] = bf2f(u.x);
            rowsT[(k4 + 1) * RST + node] = bf2f(u.y);
            rowsT[(k4 + 2) * RST + node] = bf2f(u.z);
            rowsT[(k4 + 3) * RST + node] = bf2f(u.w);
        }
        __syncthreads();
        #pragma unroll 4
        for (int k = 0; k < 64; k++) {
            float4 wa = *(const float4*)&Wch[k * 64 + j8];
            float4 wb = *(const float4*)&Wch[k * 64 + j8 + 4];
            float2 rv = *(const float2*)&rowsT[k * RST + n2];
            float w[8] = {wa.x, wa.y, wa.z, wa.w, wb.x, wb.y, wb.z, wb.w};
            float rr[2] = {rv.x, rv.y};
            #pragma unroll
            for (int i = 0; i < 2; i++)
                #pragma unroll
                for (int c = 0; c < 8; c++)
                    acc[i][c] = fmaf(rr[i], w[c], acc[i][c]);
        }
    }

    // relu epilogue into registers
    float o[2][8];
    #pragma unroll
    for (int i = 0; i < 2; i++)
        #pragma unroll
        for (int c = 0; c < 8; c++)
            o[i][c] = fmaxf(acc[i][c] + bias[j8 + c], 0.f);

    __syncthreads();   // everyone done reading Wch/rowsT/bias

    // restage: Wch <- linW (64x32), bias <- linb, rowsT <- h2 tile transposed
    #pragma unroll
    for (int r = 0; r < 2; r++) {
        int i = tid + 256 * r;   // 512 float4 = 2048 floats
        *(float4*)&Wch[i * 4] = *(const float4*)&linW[i * 4];
    }
    if (tid < 32) bias[tid] = linb[tid];
    #pragma unroll
    for (int i = 0; i < 2; i++)
        #pragma unroll
        for (int c = 0; c < 8; c++)
            rowsT[(j8 + c) * RST + (n2 + i)] = o[i][c];
    __syncthreads();

    // mini-GEMM: out[64 x 32] = h2_tile @ linW + linb
    int j4 = (tid & 7) * 4;
    float acc2[2][4];
    #pragma unroll
    for (int i = 0; i < 2; i++)
        #pragma unroll
        for (int c = 0; c < 4; c++) acc2[i][c] = 0.f;
    #pragma unroll 4
    for (int k = 0; k < 64; k++) {
        float4 w = *(const float4*)&Wch[k * 32 + j4];
        float2 rv = *(const float2*)&rowsT[k * RST + n2];
        float wr[4] = {w.x, w.y, w.z, w.w};
        float rr[2] = {rv.x, rv.y};
        #pragma unroll
        for (int i = 0; i < 2; i++)
            #pragma unroll
            for (int c = 0; c < 4; c++)
                acc2[i][c] = fmaf(rr[i], wr[c], acc2[i][c]);
    }
    #pragma unroll
    for (int i = 0; i < 2; i++) {
        int g = base + n2 + i;
        if (g < NN) {
            float4 ov;
            ov.x = acc2[i][0] + bias[j4 + 0];
            ov.y = acc2[i][1] + bias[j4 + 1];
            ov.z = acc2[i][2] + bias[j4 + 2];
            ov.w = acc2[i][3] + bias[j4 + 3];
            *(float4*)&out[(size_t)g * 32 + j4] = ov;
        }
    }
}

extern "C" void kernel_launch(void* const* d_in, const int* in_sizes, int n_in,
                              void* d_out, int out_size, void* d_ws, size_t ws_size,
                              hipStream_t stream)
{
    const float* x    = (const float*)d_in[0];
    const int*   ei0  = (const int*)d_in[1];
    const int*   ei1  = (const int*)d_in[2];
    const float* Wl   = (const float*)d_in[3];   // [2,2,64,64]
    const float* Wr   = (const float*)d_in[4];   // [2,2,64,64]
    const float* bl   = (const float*)d_in[5];   // [2,2,64]
    const float* linW = (const float*)d_in[6];   // [64,32]
    const float* linb = (const float*)d_in[7];   // [32]
    float* out = (float*)d_out;

    int E0 = in_sizes[1] / 2;
    int E1 = in_sizes[2] / 2;

    // Workspace (~32.4MB); binning scratch aliases dead regions:
    // [bins 6.4 | h1b 6.4 | aggb 12.8 | xb 6.4 | deg 0.4 | ovf]
    //   compact (6.4MB u32[E0+E1])   aliases h1b  (dead until layer_gemm)
    //   hist16 [2][NSH][NPB] 1.6MB   aliases aggb+0
    //   pbase  [2][NSH][NPB] 3.2MB   aliases aggb+1.6M
    //   tot/sbase (~13KB)            aliases aggb+4.8M
    unsigned short* bins = (unsigned short*)d_ws;
    unsigned short* h1b  = bins + (size_t)2 * NN * CAP;
    unsigned short* aggb = h1b + (size_t)NN * 64;
    unsigned short* agg0 = aggb;
    unsigned short* agg1 = aggb + (size_t)NN * 64;
    unsigned short* xb   = aggb + (size_t)2 * NN * 64;
    int*  deg     = (int*)(xb + (size_t)NN * 64);
    int*  ovf_cnt = deg + 2 * NN;
    int2* ovf     = (int2*)(ovf_cnt + 8);

    unsigned*       compact = (unsigned*)h1b;
    unsigned short* hist16  = aggb;
    unsigned*       pbase   = (unsigned*)(aggb + (size_t)2 * NSH * NPB);
    int*            tot     = (int*)(aggb + (size_t)2 * NSH * NPB * 3);
    int*            sbase   = tot + 2 * NSH;

    dim3 blk(256);
    int ggrid = (NN + 63) / 64;                 // 782

    // ---- fused binning (1 cooperative launch replaces 7) ----
    void* kargs[] = {
        (void*)&x, (void*)&xb, (void*)&ei0, (void*)&E0, (void*)&ei1, (void*)&E1,
        (void*)&hist16, (void*)&tot, (void*)&sbase, (void*)&pbase,
        (void*)&compact, (void*)&bins, (void*)&deg, (void*)&ovf, (void*)&ovf_cnt
    };
    hipLaunchCooperativeKernel((void*)binning_coop, dim3(2 * NPB), blk,
                               kargs, 0, stream);

    // ---- Layer 0 (gather + self from xb; h1b bf16 out) ----
    aggregate<<<4096, blk, 0, stream>>>(bins, deg, xb, aggb, ovf, ovf_cnt);
    layer_gemm<<<ggrid, blk, 0, stream>>>(agg0, agg1, xb,
        Wl + 0, Wl + 4096, Wr + 0, Wr + 4096, bl + 0, bl + 64, h1b);

    // ---- Layer 1 + final projection fused (h2 never materialized) ----
    aggregate<<<4096, blk, 0, stream>>>(bins, deg, h1b, aggb, ovf, ovf_cnt);
    layer_gemm_final<<<ggrid, blk, 0, stream>>>(agg0, agg1, h1b,
        Wl + 8192, Wl + 12288, Wr + 8192, Wr + 12288, bl + 128, bl + 192,
        linW, linb, out);
}

// Round 11
// 243.645 us; speedup vs baseline: 3.2750x; 3.2750x over previous
//
#include <hip/hip_runtime.h>

#define NN 50000
#define CAP 32          // per-node bin capacity; overflow handled correctly
#define OVF_CAP 4096
#define SHARD_W 64      // 64-node shards; one bin_pass block OWNS a shard
#define NSH 782         // ceil(50000/64)
#define NPB 512         // R6-proven (1024 regressed R8; coop fusion regressed R10)

__device__ __forceinline__ unsigned short f2bf(float f) {
    unsigned u = __float_as_uint(f);
    u += 0x7fffu + ((u >> 16) & 1u);           // round-to-nearest-even
    return (unsigned short)(u >> 16);
}
__device__ __forceinline__ float bf2f(unsigned short u) {
    return __uint_as_float(((unsigned)u) << 16);
}

// ---- R22: R6 pipeline restored exactly (245.2us best). R10's cooperative
// fusion REVERTED: grid.sync() on 8 XCDs costs ~85us each (binning_coop
// 596us @ VALU 0.5% — pure sync wait). Stream-ordered launches win on CDNA4.
// Only change vs R6: init_fuse folded into shard_hist (x->bf16 convert is
// grid-strided before the histogram; xb not consumed until aggregate). ----

__global__ __launch_bounds__(256) void shard_hist(
    const float* __restrict__ x, unsigned short* __restrict__ xb,
    const int* __restrict__ ei0, int E0,
    const int* __restrict__ ei1, int E1,
    unsigned short* __restrict__ hist16,        // [2][NSH][NPB] (aliases aggb)
    int* __restrict__ ovf_cnt)
{
    // P0: x -> bf16 (grid-strided; independent of histogram below)
    int gtid = blockIdx.x * 256 + threadIdx.x;
    int gsz  = gridDim.x * 256;
    for (int i = gtid; i < NN * 16; i += gsz) {
        float4 v = ((const float4*)x)[i];
        ushort4 o;
        o.x = f2bf(v.x); o.y = f2bf(v.y); o.z = f2bf(v.z); o.w = f2bf(v.w);
        ((ushort4*)xb)[i] = o;
    }
    if (gtid < 8) ovf_cnt[gtid] = 0;

    __shared__ unsigned lh[NSH];
    int local = blockIdx.x; int rel = 0;
    if (local >= NPB) { local -= NPB; rel = 1; }
    int pb = (local & 7) * (NPB / 8) + (local >> 3);
    const int* ei = rel ? ei1 : ei0;
    int E         = rel ? E1  : E0;
    int ce = (E + NPB - 1) / NPB;
    int lo = pb * ce, hi = min(lo + ce, E);

    for (int i = threadIdx.x; i < NSH; i += 256) lh[i] = 0;
    __syncthreads();
    for (int t = lo + threadIdx.x; t < hi; t += 256)
        atomicAdd(&lh[ei[E + t] >> 6], 1u);
    __syncthreads();
    for (int i = threadIdx.x; i < NSH; i += 256)
        hist16[((size_t)rel * NSH + i) * NPB + pb] = (unsigned short)lh[i];
}

// One wave per (rel,shard): coalesced row reduce.
__global__ __launch_bounds__(256) void total_pass(
    const unsigned short* __restrict__ hist16, int* __restrict__ tot)
{
    int gw = (blockIdx.x * 256 + threadIdx.x) >> 6;
    int lane = threadIdx.x & 63;
    if (gw >= 2 * NSH) return;
    uint4 v = ((const uint4*)(hist16 + (size_t)gw * NPB))[lane];
    unsigned s = (v.x & 0xffffu) + (v.x >> 16) + (v.y & 0xffffu) + (v.y >> 16)
               + (v.z & 0xffffu) + (v.z >> 16) + (v.w & 0xffffu) + (v.w >> 16);
    for (int off = 32; off; off >>= 1) s += __shfl_down(s, off);
    if (lane == 0) tot[gw] = (int)s;
}

// Exclusive scan of 1564 totals -> shard bases (+ sentinel). One block.
__global__ __launch_bounds__(256) void scan_pass(
    const int* __restrict__ tot, int* __restrict__ sbase)
{
    __shared__ int ps[256];
    int t = threadIdx.x;
    int v[7];
    int s = 0;
    #pragma unroll
    for (int j = 0; j < 7; j++) {
        int i = t * 7 + j;
        v[j] = (i < 2 * NSH) ? tot[i] : 0;
        s += v[j];
    }
    ps[t] = s;
    __syncthreads();
    for (int off = 1; off < 256; off <<= 1) {
        int add = (t >= off) ? ps[t - off] : 0;
        __syncthreads();
        ps[t] += add;
        __syncthreads();
    }
    int run = (t == 0) ? 0 : ps[t - 1];
    #pragma unroll
    for (int j = 0; j < 7; j++) {
        int i = t * 7 + j;
        if (i < 2 * NSH) sbase[i] = run;
        run += v[j];
    }
    if (t == 255) sbase[2 * NSH] = run;
}

// One wave per (rel,shard): lane-local prefix + shfl_up wave scan.
__global__ __launch_bounds__(256) void blockbase_pass(
    const unsigned short* __restrict__ hist16, const int* __restrict__ sbase,
    unsigned* __restrict__ pbase)               // [2][NSH][NPB] (aliases aggb)
{
    int gw = (blockIdx.x * 256 + threadIdx.x) >> 6;
    int lane = threadIdx.x & 63;
    if (gw >= 2 * NSH) return;
    uint4 v = ((const uint4*)(hist16 + (size_t)gw * NPB))[lane];
    unsigned c[8] = {v.x & 0xffffu, v.x >> 16, v.y & 0xffffu, v.y >> 16,
                     v.z & 0xffffu, v.z >> 16, v.w & 0xffffu, v.w >> 16};
    unsigned lsum = 0;
    #pragma unroll
    for (int j = 0; j < 8; j++) lsum += c[j];
    unsigned incl = lsum;
    for (int off = 1; off < 64; off <<= 1) {
        unsigned n = __shfl_up(incl, off);
        if (lane >= off) incl += n;
    }
    unsigned run = (unsigned)sbase[gw] + incl - lsum;
    unsigned* prow = pbase + (size_t)gw * NPB + lane * 8;
    #pragma unroll
    for (int j = 0; j < 8; j++) { prow[j] = run; run += c[j]; }
}

// Scatter edges into shard-segregated compact array: entry = (dst<<16)|src.
__global__ __launch_bounds__(256) void partition_pass(
    const int* __restrict__ ei0, int E0,
    const int* __restrict__ ei1, int E1,
    const unsigned* __restrict__ pbase,
    unsigned* __restrict__ compact)             // [E0+E1] u32 (aliases h1b)
{
    __shared__ unsigned lbase[NSH];
    __shared__ unsigned lrank[NSH];
    int local = blockIdx.x; int rel = 0;
    if (local >= NPB) { local -= NPB; rel = 1; }
    int pb = (local & 7) * (NPB / 8) + (local >> 3);
    const int* ei = rel ? ei1 : ei0;
    int E         = rel ? E1  : E0;
    int ce = (E + NPB - 1) / NPB;
    int lo = pb * ce, hi = min(lo + ce, E);

    for (int i = threadIdx.x; i < NSH; i += 256) {
        lbase[i] = pbase[((size_t)rel * NSH + i) * NPB + pb];
        lrank[i] = 0;
    }
    __syncthreads();
    for (int t = lo + threadIdx.x; t < hi; t += 256) {
        int dst = ei[E + t];
        int src = ei[t];
        int s = dst >> 6;
        unsigned r = atomicAdd(&lrank[s], 1u);
        compact[lbase[s] + r] = ((unsigned)dst << 16) | (unsigned)src;
    }
}

// One block per (rel,shard): owns ALL the shard's edges -> free slot order.
__global__ __launch_bounds__(256) void bin_pass(
    const unsigned* __restrict__ compact, const int* __restrict__ sbase,
    unsigned short* __restrict__ bins, int* __restrict__ deg,
    int2* __restrict__ ovf, int* __restrict__ ovf_cnt)
{
    __shared__ unsigned lcnt[SHARD_W];
    int bid = blockIdx.x;                       // = rel*NSH + s
    int rel = bid / NSH;
    int s   = bid - rel * NSH;
    if (threadIdx.x < SHARD_W) lcnt[threadIdx.x] = 0;
    __syncthreads();
    int base = sbase[bid];
    int tot  = sbase[bid + 1] - base;
    int taskbase = rel * NN + s * SHARD_W;
    for (int j = threadIdx.x; j < tot; j += 256) {
        unsigned e = compact[base + j];
        int dst = (int)(e >> 16);
        int src = (int)(e & 0xffffu);
        int loc = dst & (SHARD_W - 1);
        unsigned r = atomicAdd(&lcnt[loc], 1u);
        int task = taskbase + loc;
        if (r < CAP) {
            bins[(size_t)task * CAP + r] = (unsigned short)src;
        } else {
            int o = atomicAdd(ovf_cnt, 1);
            if (o < OVF_CAP) ovf[o] = make_int2(task, src);
        }
    }
    __syncthreads();
    if (threadIdx.x < SHARD_W) {
        int node = s * SHARD_W + threadIdx.x;
        if (node < NN) deg[rel * NN + node] = (int)lcnt[threadIdx.x];
    }
}

// One (rel,node) task per wave; paired bf16 gathers; inline overflow pickup.
__global__ __launch_bounds__(256) void aggregate(
    const unsigned short* __restrict__ bins, const int* __restrict__ deg,
    const unsigned short* __restrict__ hb, unsigned short* __restrict__ agg,
    const int2* __restrict__ ovf, const int* __restrict__ ovf_cnt)
{
    int lane = threadIdx.x & 63;
    int half = lane >> 5;
    int p = lane & 31;                 // feature-pair index
    int wid = (blockIdx.x * blockDim.x + threadIdx.x) >> 6;
    int nwaves = (gridDim.x * blockDim.x) >> 6;
    const unsigned int* hb32 = (const unsigned int*)hb;
    unsigned int* agg32 = (unsigned int*)agg;

    for (int task = wid; task < 2 * NN; task += nwaves) {
        int d = deg[task];
        int m = min(d, CAP);
        int idx = 0;
        if (lane < m) idx = bins[(size_t)task * CAP + lane];
        float a00=0.f,a01=0.f, a10=0.f,a11=0.f, a20=0.f,a21=0.f, a30=0.f,a31=0.f;
        int F = m >> 1;                // complete pair-steps
        int q = 0;
        for (; q + 4 <= F; q += 4) {
            int s0 = __shfl(idx, 2*(q+0) + half);
            int s1 = __shfl(idx, 2*(q+1) + half);
            int s2 = __shfl(idx, 2*(q+2) + half);
            int s3 = __shfl(idx, 2*(q+3) + half);
            unsigned u0 = hb32[(size_t)s0 * 32 + p];
            unsigned u1 = hb32[(size_t)s1 * 32 + p];
            unsigned u2 = hb32[(size_t)s2 * 32 + p];
            unsigned u3 = hb32[(size_t)s3 * 32 + p];
            a00 += __uint_as_float(u0 << 16); a01 += __uint_as_float(u0 & 0xffff0000u);
            a10 += __uint_as_float(u1 << 16); a11 += __uint_as_float(u1 & 0xffff0000u);
            a20 += __uint_as_float(u2 << 16); a21 += __uint_as_float(u2 & 0xffff0000u);
            a30 += __uint_as_float(u3 << 16); a31 += __uint_as_float(u3 & 0xffff0000u);
        }
        for (; q < F; ++q) {
            int s = __shfl(idx, 2*q + half);
            unsigned u = hb32[(size_t)s * 32 + p];
            a00 += __uint_as_float(u << 16); a01 += __uint_as_float(u & 0xffff0000u);
        }
        if (m & 1) {
            int s = __shfl(idx, m - 1);
            if (half == 0) {
                unsigned u = hb32[(size_t)s * 32 + p];
                a00 += __uint_as_float(u << 16); a01 += __uint_as_float(u & 0xffff0000u);
            }
        }
        if (d > CAP) {                 // rare: pick up this task's overflow edges
            int cnt = min(*ovf_cnt, OVF_CAP);
            for (int e = 0; e < cnt; ++e) {
                int2 v = ovf[e];
                if (v.x == task && half == 0) {
                    unsigned u = hb32[(size_t)v.y * 32 + p];
                    a00 += __uint_as_float(u << 16); a01 += __uint_as_float(u & 0xffff0000u);
                }
            }
        }
        float s0 = (a00 + a10) + (a20 + a30);
        float s1 = (a01 + a11) + (a21 + a31);
        s0 += __shfl_xor(s0, 32);
        s1 += __shfl_xor(s1, 32);
        if (half == 0) {
            float inv = 1.0f / (float)max(d, 1);
            unsigned lo = (unsigned)f2bf(s0 * inv);
            unsigned hi = (unsigned)f2bf(s1 * inv);
            agg32[(size_t)task * 32 + p] = lo | (hi << 16);
        }
    }
}

// L0: h1b = bf16( relu(mean0@Wl0 + mean1@Wl1 + self@(Wr0+Wr1) + b) ).
#define RST 132
__global__ __launch_bounds__(256) void layer_gemm(
    const unsigned short* __restrict__ agg0, const unsigned short* __restrict__ agg1,
    const unsigned short* __restrict__ selfb,
    const float* __restrict__ Wl0, const float* __restrict__ Wl1,
    const float* __restrict__ Wr0, const float* __restrict__ Wr1,
    const float* __restrict__ b0, const float* __restrict__ b1,
    unsigned short* __restrict__ hb16)
{
    __shared__ float Wch[64 * 64];
    __shared__ float rowsT[64 * RST];
    __shared__ float bias[64];

    int tid = threadIdx.x;
    int base = blockIdx.x * 128;
    if (tid < 64) bias[tid] = b0[tid] + b1[tid];

    int j8 = (tid & 7) * 8;
    int n4 = (tid >> 3) * 4;

    float acc[4][8];
    #pragma unroll
    for (int i = 0; i < 4; i++)
        #pragma unroll
        for (int c = 0; c < 8; c++) acc[i][c] = 0.f;

    for (int chunk = 0; chunk < 3; chunk++) {
        const float* W = (chunk == 0) ? Wl0 : (chunk == 1) ? Wl1 : Wr0;
        const unsigned short* src = (chunk == 0) ? agg0 : (chunk == 1) ? agg1 : selfb;
        __syncthreads();
        #pragma unroll
        for (int r = 0; r < 4; r++) {
            int i = tid + 256 * r;
            float4 w = *(const float4*)&W[i * 4];
            if (chunk == 2) {
                float4 w2 = *(const float4*)&Wr1[i * 4];
                w.x += w2.x; w.y += w2.y; w.z += w2.z; w.w += w2.w;
            }
            *(float4*)&Wch[i * 4] = w;
        }
        #pragma unroll
        for (int r = 0; r < 8; r++) {
            int i = tid + 256 * r;
            int node = i >> 4;
            int k4 = (i & 15) * 4;
            int g = base + node;
            ushort4 u = make_ushort4(0, 0, 0, 0);
            if (g < NN) u = *(const ushort4*)&src[(size_t)g * 64 + k4];
            rowsT[(k4 + 0) * RST + node] = bf2f(u.x);
            rowsT[(k4 + 1) * RST + node] = bf2f(u.y);
            rowsT[(k4 + 2) * RST + node] = bf2f(u.z);
            rowsT[(k4 + 3) * RST + node] = bf2f(u.w);
        }
        __syncthreads();
        #pragma unroll 4
        for (int k = 0; k < 64; k++) {
            float4 wa = *(const float4*)&Wch[k * 64 + j8];
            float4 wb = *(const float4*)&Wch[k * 64 + j8 + 4];
            float4 rv = *(const float4*)&rowsT[k * RST + n4];
            float w[8] = {wa.x, wa.y, wa.z, wa.w, wb.x, wb.y, wb.z, wb.w};
            float rr[4] = {rv.x, rv.y, rv.z, rv.w};
            #pragma unroll
            for (int i = 0; i < 4; i++)
                #pragma unroll
                for (int c = 0; c < 8; c++)
                    acc[i][c] = fmaf(rr[i], w[c], acc[i][c]);
        }
    }

    #pragma unroll
    for (int i = 0; i < 4; i++) {
        int g = base + n4 + i;
        if (g < NN) {
            ushort4 p0, p1;
            p0.x = f2bf(fmaxf(acc[i][0] + bias[j8 + 0], 0.f));
            p0.y = f2bf(fmaxf(acc[i][1] + bias[j8 + 1], 0.f));
            p0.z = f2bf(fmaxf(acc[i][2] + bias[j8 + 2], 0.f));
            p0.w = f2bf(fmaxf(acc[i][3] + bias[j8 + 3], 0.f));
            p1.x = f2bf(fmaxf(acc[i][4] + bias[j8 + 4], 0.f));
            p1.y = f2bf(fmaxf(acc[i][5] + bias[j8 + 5], 0.f));
            p1.z = f2bf(fmaxf(acc[i][6] + bias[j8 + 6], 0.f));
            p1.w = f2bf(fmaxf(acc[i][7] + bias[j8 + 7], 0.f));
            *(ushort4*)&hb16[(size_t)g * 64 + j8]     = p0;
            *(ushort4*)&hb16[(size_t)g * 64 + j8 + 4] = p1;
        }
    }
}

// L1 + final fused: h2 tile in LDS, then out = h2 @ linW + linb.
__global__ __launch_bounds__(256) void layer_gemm_final(
    const unsigned short* __restrict__ agg0, const unsigned short* __restrict__ agg1,
    const unsigned short* __restrict__ selfb,
    const float* __restrict__ Wl0, const float* __restrict__ Wl1,
    const float* __restrict__ Wr0, const float* __restrict__ Wr1,
    const float* __restrict__ b0, const float* __restrict__ b1,
    const float* __restrict__ linW, const float* __restrict__ linb,
    float* __restrict__ out)
{
    __shared__ float Wch[64 * 64];
    __shared__ float rowsT[64 * RST];
    __shared__ float bias[64];

    int tid = threadIdx.x;
    int base = blockIdx.x * 128;
    if (tid < 64) bias[tid] = b0[tid] + b1[tid];

    int j8 = (tid & 7) * 8;
    int n4 = (tid >> 3) * 4;

    float acc[4][8];
    #pragma unroll
    for (int i = 0; i < 4; i++)
        #pragma unroll
        for (int c = 0; c < 8; c++) acc[i][c] = 0.f;

    for (int chunk = 0; chunk < 3; chunk++) {
        const float* W = (chunk == 0) ? Wl0 : (chunk == 1) ? Wl1 : Wr0;
        const unsigned short* src = (chunk == 0) ? agg0 : (chunk == 1) ? agg1 : selfb;
        __syncthreads();
        #pragma unroll
        for (int r = 0; r < 4; r++) {
            int i = tid + 256 * r;
            float4 w = *(const float4*)&W[i * 4];
            if (chunk == 2) {
                float4 w2 = *(const float4*)&Wr1[i * 4];
                w.x += w2.x; w.y += w2.y; w.z += w2.z; w.w += w2.w;
            }
            *(float4*)&Wch[i * 4] = w;
        }
        #pragma unroll
        for (int r = 0; r < 8; r++) {
            int i = tid + 256 * r;
            int node = i >> 4;
            int k4 = (i & 15) * 4;
            int g = base + node;
            ushort4 u = make_ushort4(0, 0, 0, 0);
            if (g < NN) u = *(const ushort4*)&src[(size_t)g * 64 + k4];
            rowsT[(k4 + 0) * RST + node] = bf2f(u.x);
            rowsT[(k4 + 1) * RST + node] = bf2f(u.y);
            rowsT[(k4 + 2) * RST + node] = bf2f(u.z);
            rowsT[(k4 + 3) * RST + node] = bf2f(u.w);
        }
        __syncthreads();
        #pragma unroll 4
        for (int k = 0; k < 64; k++) {
            float4 wa = *(const float4*)&Wch[k * 64 + j8];
            float4 wb = *(const float4*)&Wch[k * 64 + j8 + 4];
            float4 rv = *(const float4*)&rowsT[k * RST + n4];
            float w[8] = {wa.x, wa.y, wa.z, wa.w, wb.x, wb.y, wb.z, wb.w};
            float rr[4] = {rv.x, rv.y, rv.z, rv.w};
            #pragma unroll
            for (int i = 0; i < 4; i++)
                #pragma unroll
                for (int c = 0; c < 8; c++)
                    acc[i][c] = fmaf(rr[i], w[c], acc[i][c]);
        }
    }

    // relu epilogue into registers
    float o[4][8];
    #pragma unroll
    for (int i = 0; i < 4; i++)
        #pragma unroll
        for (int c = 0; c < 8; c++)
            o[i][c] = fmaxf(acc[i][c] + bias[j8 + c], 0.f);

    __syncthreads();   // everyone done reading Wch/rowsT/bias

    // restage: Wch <- linW (64x32), bias <- linb, rowsT <- h2 tile transposed
    #pragma unroll
    for (int r = 0; r < 2; r++) {
        int i = tid + 256 * r;   // 512 float4 = 2048 floats
        *(float4*)&Wch[i * 4] = *(const float4*)&linW[i * 4];
    }
    if (tid < 32) bias[tid] = linb[tid];
    #pragma unroll
    for (int i = 0; i < 4; i++)
        #pragma unroll
        for (int c = 0; c < 8; c++)
            rowsT[(j8 + c) * RST + (n4 + i)] = o[i][c];
    __syncthreads();

    // mini-GEMM: out[128 x 32] = h2_tile @ linW + linb
    int j4 = (tid & 7) * 4;
    float acc2[4][4];
    #pragma unroll
    for (int i = 0; i < 4; i++)
        #pragma unroll
        for (int c = 0; c < 4; c++) acc2[i][c] = 0.f;
    #pragma unroll 4
    for (int k = 0; k < 64; k++) {
        float4 w = *(const float4*)&Wch[k * 32 + j4];
        float4 rv = *(const float4*)&rowsT[k * RST + n4];
        float wr[4] = {w.x, w.y, w.z, w.w};
        float rr[4] = {rv.x, rv.y, rv.z, rv.w};
        #pragma unroll
        for (int i = 0; i < 4; i++)
            #pragma unroll
            for (int c = 0; c < 4; c++)
                acc2[i][c] = fmaf(rr[i], wr[c], acc2[i][c]);
    }
    #pragma unroll
    for (int i = 0; i < 4; i++) {
        int g = base + n4 + i;
        if (g < NN) {
            float4 ov;
            ov.x = acc2[i][0] + bias[j4 + 0];
            ov.y = acc2[i][1] + bias[j4 + 1];
            ov.z = acc2[i][2] + bias[j4 + 2];
            ov.w = acc2[i][3] + bias[j4 + 3];
            *(float4*)&out[(size_t)g * 32 + j4] = ov;
        }
    }
}

extern "C" void kernel_launch(void* const* d_in, const int* in_sizes, int n_in,
                              void* d_out, int out_size, void* d_ws, size_t ws_size,
                              hipStream_t stream)
{
    const float* x    = (const float*)d_in[0];
    const int*   ei0  = (const int*)d_in[1];
    const int*   ei1  = (const int*)d_in[2];
    const float* Wl   = (const float*)d_in[3];   // [2,2,64,64]
    const float* Wr   = (const float*)d_in[4];   // [2,2,64,64]
    const float* bl   = (const float*)d_in[5];   // [2,2,64]
    const float* linW = (const float*)d_in[6];   // [64,32]
    const float* linb = (const float*)d_in[7];   // [32]
    float* out = (float*)d_out;

    int E0 = in_sizes[1] / 2;
    int E1 = in_sizes[2] / 2;

    // Workspace (~32.4MB); binning scratch aliases dead regions:
    // [bins 6.4 | h1b 6.4 | aggb 12.8 | xb 6.4 | deg 0.4 | ovf]
    //   compact (6.4MB u32[E0+E1])   aliases h1b  (dead until layer_gemm)
    //   hist16 [2][NSH][NPB] 1.6MB   aliases aggb+0
    //   pbase  [2][NSH][NPB] 3.2MB   aliases aggb+1.6M
    //   tot/sbase (~13KB)            aliases aggb+4.8M
    unsigned short* bins = (unsigned short*)d_ws;
    unsigned short* h1b  = bins + (size_t)2 * NN * CAP;
    unsigned short* aggb = h1b + (size_t)NN * 64;
    unsigned short* agg0 = aggb;
    unsigned short* agg1 = aggb + (size_t)NN * 64;
    unsigned short* xb   = aggb + (size_t)2 * NN * 64;
    int*  deg     = (int*)(xb + (size_t)NN * 64);
    int*  ovf_cnt = deg + 2 * NN;
    int2* ovf     = (int2*)(ovf_cnt + 8);

    unsigned*       compact = (unsigned*)h1b;
    unsigned short* hist16  = aggb;
    unsigned*       pbase   = (unsigned*)(aggb + (size_t)2 * NSH * NPB);
    int*            tot     = (int*)(aggb + (size_t)2 * NSH * NPB * 3);
    int*            sbase   = tot + 2 * NSH;

    dim3 blk(256);
    int ggrid = (NN + 127) / 128;               // 391
    int wave_grid = (2 * NSH * 64 + 255) / 256; // 391: 1 wave/(rel,shard)

    // ---- shard-partition binning (R6-proven; init folded into hist) ----
    shard_hist<<<2 * NPB, blk, 0, stream>>>(x, xb, ei0, E0, ei1, E1,
                                            hist16, ovf_cnt);
    total_pass<<<wave_grid, blk, 0, stream>>>(hist16, tot);
    scan_pass<<<1, blk, 0, stream>>>(tot, sbase);
    blockbase_pass<<<wave_grid, blk, 0, stream>>>(hist16, sbase, pbase);
    partition_pass<<<2 * NPB, blk, 0, stream>>>(ei0, E0, ei1, E1, pbase, compact);
    bin_pass<<<2 * NSH, blk, 0, stream>>>(compact, sbase, bins, deg, ovf, ovf_cnt);

    // ---- Layer 0 (gather + self from xb; h1b bf16 out) ----
    aggregate<<<4096, blk, 0, stream>>>(bins, deg, xb, aggb, ovf, ovf_cnt);
    layer_gemm<<<ggrid, blk, 0, stream>>>(agg0, agg1, xb,
        Wl + 0, Wl + 4096, Wr + 0, Wr + 4096, bl + 0, bl + 64, h1b);

    // ---- Layer 1 + final projection fused (h2 never materialized) ----
    aggregate<<<4096, blk, 0, stream>>>(bins, deg, h1b, aggb, ovf, ovf_cnt);
    layer_gemm_final<<<ggrid, blk, 0, stream>>>(agg0, agg1, h1b,
        Wl + 8192, Wl + 12288, Wr + 8192, Wr + 12288, bl + 128, bl + 192,
        linW, linb, out);
}

// Round 12
// 241.856 us; speedup vs baseline: 3.2992x; 1.0074x over previous
//
#include <hip/hip_runtime.h>

#define NN 50000
#define CAP 32          // per-node bin capacity (semantics unchanged)
#define OVF_LDS 1024    // per-shard LDS overflow list (Poisson-16 tail << this)
#define SHARD_W 64      // 64-node shards
#define NSH 782         // ceil(50000/64)
#define NPB 512         // R6-proven

__device__ __forceinline__ unsigned short f2bf(float f) {
    unsigned u = __float_as_uint(f);
    u += 0x7fffu + ((u >> 16) & 1u);           // round-to-nearest-even
    return (unsigned short)(u >> 16);
}
__device__ __forceinline__ float bf2f(unsigned short u) {
    return __uint_as_float(((unsigned)u) << 16);
}

// ---- R23: bin_pass fused INTO aggregate via LDS bins ----
// R22 = 243.6us best. bins was a pure intermediary: written once, read twice
// (~19MB + 1 launch). Each (rel,shard)'s edges are contiguous in compact, so
// each aggregate block LDS-sorts its segment (4KB bins + local ovf) then runs
// the PROVEN shfl-gather loop reading bins from LDS. compact relocated to the
// freed bins slot (it must now outlive gemm0's h1b write).

__global__ __launch_bounds__(256) void shard_hist(
    const float* __restrict__ x, unsigned short* __restrict__ xb,
    const int* __restrict__ ei0, int E0,
    const int* __restrict__ ei1, int E1,
    unsigned short* __restrict__ hist16)        // [2][NSH][NPB] (aliases aggb)
{
    // P0: x -> bf16 (grid-strided; xb not consumed until aggregate L0)
    int gtid = blockIdx.x * 256 + threadIdx.x;
    int gsz  = gridDim.x * 256;
    for (int i = gtid; i < NN * 16; i += gsz) {
        float4 v = ((const float4*)x)[i];
        ushort4 o;
        o.x = f2bf(v.x); o.y = f2bf(v.y); o.z = f2bf(v.z); o.w = f2bf(v.w);
        ((ushort4*)xb)[i] = o;
    }

    __shared__ unsigned lh[NSH];
    int local = blockIdx.x; int rel = 0;
    if (local >= NPB) { local -= NPB; rel = 1; }
    int pb = (local & 7) * (NPB / 8) + (local >> 3);
    const int* ei = rel ? ei1 : ei0;
    int E         = rel ? E1  : E0;
    int ce = (E + NPB - 1) / NPB;
    int lo = pb * ce, hi = min(lo + ce, E);

    for (int i = threadIdx.x; i < NSH; i += 256) lh[i] = 0;
    __syncthreads();
    for (int t = lo + threadIdx.x; t < hi; t += 256)
        atomicAdd(&lh[ei[E + t] >> 6], 1u);
    __syncthreads();
    for (int i = threadIdx.x; i < NSH; i += 256)
        hist16[((size_t)rel * NSH + i) * NPB + pb] = (unsigned short)lh[i];
}

// One wave per (rel,shard): coalesced row reduce.
__global__ __launch_bounds__(256) void total_pass(
    const unsigned short* __restrict__ hist16, int* __restrict__ tot)
{
    int gw = (blockIdx.x * 256 + threadIdx.x) >> 6;
    int lane = threadIdx.x & 63;
    if (gw >= 2 * NSH) return;
    uint4 v = ((const uint4*)(hist16 + (size_t)gw * NPB))[lane];
    unsigned s = (v.x & 0xffffu) + (v.x >> 16) + (v.y & 0xffffu) + (v.y >> 16)
               + (v.z & 0xffffu) + (v.z >> 16) + (v.w & 0xffffu) + (v.w >> 16);
    for (int off = 32; off; off >>= 1) s += __shfl_down(s, off);
    if (lane == 0) tot[gw] = (int)s;
}

// Exclusive scan of 1564 totals -> shard bases (+ sentinel). One block.
__global__ __launch_bounds__(256) void scan_pass(
    const int* __restrict__ tot, int* __restrict__ sbase)
{
    __shared__ int ps[256];
    int t = threadIdx.x;
    int v[7];
    int s = 0;
    #pragma unroll
    for (int j = 0; j < 7; j++) {
        int i = t * 7 + j;
        v[j] = (i < 2 * NSH) ? tot[i] : 0;
        s += v[j];
    }
    ps[t] = s;
    __syncthreads();
    for (int off = 1; off < 256; off <<= 1) {
        int add = (t >= off) ? ps[t - off] : 0;
        __syncthreads();
        ps[t] += add;
        __syncthreads();
    }
    int run = (t == 0) ? 0 : ps[t - 1];
    #pragma unroll
    for (int j = 0; j < 7; j++) {
        int i = t * 7 + j;
        if (i < 2 * NSH) sbase[i] = run;
        run += v[j];
    }
    if (t == 255) sbase[2 * NSH] = run;
}

// One wave per (rel,shard): lane-local prefix + shfl_up wave scan.
__global__ __launch_bounds__(256) void blockbase_pass(
    const unsigned short* __restrict__ hist16, const int* __restrict__ sbase,
    unsigned* __restrict__ pbase)               // [2][NSH][NPB] (aliases aggb)
{
    int gw = (blockIdx.x * 256 + threadIdx.x) >> 6;
    int lane = threadIdx.x & 63;
    if (gw >= 2 * NSH) return;
    uint4 v = ((const uint4*)(hist16 + (size_t)gw * NPB))[lane];
    unsigned c[8] = {v.x & 0xffffu, v.x >> 16, v.y & 0xffffu, v.y >> 16,
                     v.z & 0xffffu, v.z >> 16, v.w & 0xffffu, v.w >> 16};
    unsigned lsum = 0;
    #pragma unroll
    for (int j = 0; j < 8; j++) lsum += c[j];
    unsigned incl = lsum;
    for (int off = 1; off < 64; off <<= 1) {
        unsigned n = __shfl_up(incl, off);
        if (lane >= off) incl += n;
    }
    unsigned run = (unsigned)sbase[gw] + incl - lsum;
    unsigned* prow = pbase + (size_t)gw * NPB + lane * 8;
    #pragma unroll
    for (int j = 0; j < 8; j++) { prow[j] = run; run += c[j]; }
}

// Scatter edges into shard-segregated compact array: entry = (dst<<16)|src.
__global__ __launch_bounds__(256) void partition_pass(
    const int* __restrict__ ei0, int E0,
    const int* __restrict__ ei1, int E1,
    const unsigned* __restrict__ pbase,
    unsigned* __restrict__ compact)             // [E0+E1] u32 (old bins slot)
{
    __shared__ unsigned lbase[NSH];
    __shared__ unsigned lrank[NSH];
    int local = blockIdx.x; int rel = 0;
    if (local >= NPB) { local -= NPB; rel = 1; }
    int pb = (local & 7) * (NPB / 8) + (local >> 3);
    const int* ei = rel ? ei1 : ei0;
    int E         = rel ? E1  : E0;
    int ce = (E + NPB - 1) / NPB;
    int lo = pb * ce, hi = min(lo + ce, E);

    for (int i = threadIdx.x; i < NSH; i += 256) {
        lbase[i] = pbase[((size_t)rel * NSH + i) * NPB + pb];
        lrank[i] = 0;
    }
    __syncthreads();
    for (int t = lo + threadIdx.x; t < hi; t += 256) {
        int dst = ei[E + t];
        int src = ei[t];
        int s = dst >> 6;
        unsigned r = atomicAdd(&lrank[s], 1u);
        compact[lbase[s] + r] = ((unsigned)dst << 16) | (unsigned)src;
    }
}

// Fused bin+aggregate: one block per (rel,shard). LDS-sort the contiguous
// compact segment into per-node bins (CAP=32 + local overflow), then run the
// proven wave shfl-gather aggregate reading bins from LDS. Registers hold all
// accumulation (NOT R18's ds_add_f32 design).
__global__ __launch_bounds__(256) void aggregate_shard(
    const unsigned* __restrict__ compact, const int* __restrict__ sbase,
    const unsigned short* __restrict__ hb, unsigned short* __restrict__ agg)
{
    __shared__ unsigned short lbins[SHARD_W * CAP];   // 4KB
    __shared__ unsigned lcnt[SHARD_W];                // 256B
    __shared__ unsigned lovf[OVF_LDS];                // 4KB
    __shared__ unsigned lovf_cnt;

    int bid = blockIdx.x;                       // = rel*NSH + s
    int rel = bid / NSH;
    int s   = bid - rel * NSH;
    int tid = threadIdx.x;
    int lane = tid & 63;
    int half = lane >> 5;
    int p = lane & 31;
    int wid = tid >> 6;                         // 0..3

    if (tid < SHARD_W) lcnt[tid] = 0;
    if (tid == 0) lovf_cnt = 0;
    __syncthreads();

    // Phase 1: LDS bin (identical semantics to old bin_pass, local ovf).
    int base = sbase[bid];
    int tt   = sbase[bid + 1] - base;
    for (int j = tid; j < tt; j += 256) {
        unsigned e = compact[base + j];
        int loc = (int)(e >> 16) & (SHARD_W - 1);
        unsigned r = atomicAdd(&lcnt[loc], 1u);
        if (r < CAP) {
            lbins[loc * CAP + r] = (unsigned short)(e & 0xffffu);
        } else {
            unsigned o = atomicAdd(&lovf_cnt, 1u);
            if (o < OVF_LDS) lovf[o] = ((unsigned)loc << 16) | (e & 0xffffu);
        }
    }
    __syncthreads();

    // Phase 2: proven shfl-gather aggregate; wave w owns nodes w*16..w*16+15.
    const unsigned* hb32 = (const unsigned*)hb;
    unsigned* agg32 = (unsigned*)agg;
    for (int t = 0; t < 16; ++t) {
        int loc = wid * 16 + t;
        int d = (int)lcnt[loc];
        int m = min(d, CAP);
        int idx = 0;
        if (lane < m) idx = lbins[loc * CAP + lane];
        float a00=0.f,a01=0.f, a10=0.f,a11=0.f, a20=0.f,a21=0.f, a30=0.f,a31=0.f;
        int F = m >> 1;
        int q = 0;
        for (; q + 4 <= F; q += 4) {
            int s0 = __shfl(idx, 2*(q+0) + half);
            int s1 = __shfl(idx, 2*(q+1) + half);
            int s2 = __shfl(idx, 2*(q+2) + half);
            int s3 = __shfl(idx, 2*(q+3) + half);
            unsigned u0 = hb32[(size_t)s0 * 32 + p];
            unsigned u1 = hb32[(size_t)s1 * 32 + p];
            unsigned u2 = hb32[(size_t)s2 * 32 + p];
            unsigned u3 = hb32[(size_t)s3 * 32 + p];
            a00 += __uint_as_float(u0 << 16); a01 += __uint_as_float(u0 & 0xffff0000u);
            a10 += __uint_as_float(u1 << 16); a11 += __uint_as_float(u1 & 0xffff0000u);
            a20 += __uint_as_float(u2 << 16); a21 += __uint_as_float(u2 & 0xffff0000u);
            a30 += __uint_as_float(u3 << 16); a31 += __uint_as_float(u3 & 0xffff0000u);
        }
        for (; q < F; ++q) {
            int s0 = __shfl(idx, 2*q + half);
            unsigned u = hb32[(size_t)s0 * 32 + p];
            a00 += __uint_as_float(u << 16); a01 += __uint_as_float(u & 0xffff0000u);
        }
        if (m & 1) {
            int s0 = __shfl(idx, m - 1);
            if (half == 0) {
                unsigned u = hb32[(size_t)s0 * 32 + p];
                a00 += __uint_as_float(u << 16); a01 += __uint_as_float(u & 0xffff0000u);
            }
        }
        if (d > CAP) {                 // rare: this shard's local overflow
            int cnt = min((int)lovf_cnt, OVF_LDS);
            for (int e0 = 0; e0 < cnt; ++e0) {
                unsigned v = lovf[e0];
                if ((int)(v >> 16) == loc && half == 0) {
                    unsigned u = hb32[(size_t)(v & 0xffffu) * 32 + p];
                    a00 += __uint_as_float(u << 16); a01 += __uint_as_float(u & 0xffff0000u);
                }
            }
        }
        float s0 = (a00 + a10) + (a20 + a30);
        float s1 = (a01 + a11) + (a21 + a31);
        s0 += __shfl_xor(s0, 32);
        s1 += __shfl_xor(s1, 32);
        int node = s * SHARD_W + loc;
        if (half == 0 && node < NN) {
            float inv = 1.0f / (float)max(d, 1);
            unsigned lo = (unsigned)f2bf(s0 * inv);
            unsigned hi = (unsigned)f2bf(s1 * inv);
            agg32[((size_t)rel * NN + node) * 32 + p] = lo | (hi << 16);
        }
    }
}

// L0: h1b = bf16( relu(mean0@Wl0 + mean1@Wl1 + self@(Wr0+Wr1) + b) ).
#define RST 132
__global__ __launch_bounds__(256) void layer_gemm(
    const unsigned short* __restrict__ agg0, const unsigned short* __restrict__ agg1,
    const unsigned short* __restrict__ selfb,
    const float* __restrict__ Wl0, const float* __restrict__ Wl1,
    const float* __restrict__ Wr0, const float* __restrict__ Wr1,
    const float* __restrict__ b0, const float* __restrict__ b1,
    unsigned short* __restrict__ hb16)
{
    __shared__ float Wch[64 * 64];
    __shared__ float rowsT[64 * RST];
    __shared__ float bias[64];

    int tid = threadIdx.x;
    int base = blockIdx.x * 128;
    if (tid < 64) bias[tid] = b0[tid] + b1[tid];

    int j8 = (tid & 7) * 8;
    int n4 = (tid >> 3) * 4;

    float acc[4][8];
    #pragma unroll
    for (int i = 0; i < 4; i++)
        #pragma unroll
        for (int c = 0; c < 8; c++) acc[i][c] = 0.f;

    for (int chunk = 0; chunk < 3; chunk++) {
        const float* W = (chunk == 0) ? Wl0 : (chunk == 1) ? Wl1 : Wr0;
        const unsigned short* src = (chunk == 0) ? agg0 : (chunk == 1) ? agg1 : selfb;
        __syncthreads();
        #pragma unroll
        for (int r = 0; r < 4; r++) {
            int i = tid + 256 * r;
            float4 w = *(const float4*)&W[i * 4];
            if (chunk == 2) {
                float4 w2 = *(const float4*)&Wr1[i * 4];
                w.x += w2.x; w.y += w2.y; w.z += w2.z; w.w += w2.w;
            }
            *(float4*)&Wch[i * 4] = w;
        }
        #pragma unroll
        for (int r = 0; r < 8; r++) {
            int i = tid + 256 * r;
            int node = i >> 4;
            int k4 = (i & 15) * 4;
            int g = base + node;
            ushort4 u = make_ushort4(0, 0, 0, 0);
            if (g < NN) u = *(const ushort4*)&src[(size_t)g * 64 + k4];
            rowsT[(k4 + 0) * RST + node] = bf2f(u.x);
            rowsT[(k4 + 1) * RST + node] = bf2f(u.y);
            rowsT[(k4 + 2) * RST + node] = bf2f(u.z);
            rowsT[(k4 + 3) * RST + node] = bf2f(u.w);
        }
        __syncthreads();
        #pragma unroll 4
        for (int k = 0; k < 64; k++) {
            float4 wa = *(const float4*)&Wch[k * 64 + j8];
            float4 wb = *(const float4*)&Wch[k * 64 + j8 + 4];
            float4 rv = *(const float4*)&rowsT[k * RST + n4];
            float w[8] = {wa.x, wa.y, wa.z, wa.w, wb.x, wb.y, wb.z, wb.w};
            float rr[4] = {rv.x, rv.y, rv.z, rv.w};
            #pragma unroll
            for (int i = 0; i < 4; i++)
                #pragma unroll
                for (int c = 0; c < 8; c++)
                    acc[i][c] = fmaf(rr[i], w[c], acc[i][c]);
        }
    }

    #pragma unroll
    for (int i = 0; i < 4; i++) {
        int g = base + n4 + i;
        if (g < NN) {
            ushort4 p0, p1;
            p0.x = f2bf(fmaxf(acc[i][0] + bias[j8 + 0], 0.f));
            p0.y = f2bf(fmaxf(acc[i][1] + bias[j8 + 1], 0.f));
            p0.z = f2bf(fmaxf(acc[i][2] + bias[j8 + 2], 0.f));
            p0.w = f2bf(fmaxf(acc[i][3] + bias[j8 + 3], 0.f));
            p1.x = f2bf(fmaxf(acc[i][4] + bias[j8 + 4], 0.f));
            p1.y = f2bf(fmaxf(acc[i][5] + bias[j8 + 5], 0.f));
            p1.z = f2bf(fmaxf(acc[i][6] + bias[j8 + 6], 0.f));
            p1.w = f2bf(fmaxf(acc[i][7] + bias[j8 + 7], 0.f));
            *(ushort4*)&hb16[(size_t)g * 64 + j8]     = p0;
            *(ushort4*)&hb16[(size_t)g * 64 + j8 + 4] = p1;
        }
    }
}

// L1 + final fused: h2 tile in LDS, then out = h2 @ linW + linb.
__global__ __launch_bounds__(256) void layer_gemm_final(
    const unsigned short* __restrict__ agg0, const unsigned short* __restrict__ agg1,
    const unsigned short* __restrict__ selfb,
    const float* __restrict__ Wl0, const float* __restrict__ Wl1,
    const float* __restrict__ Wr0, const float* __restrict__ Wr1,
    const float* __restrict__ b0, const float* __restrict__ b1,
    const float* __restrict__ linW, const float* __restrict__ linb,
    float* __restrict__ out)
{
    __shared__ float Wch[64 * 64];
    __shared__ float rowsT[64 * RST];
    __shared__ float bias[64];

    int tid = threadIdx.x;
    int base = blockIdx.x * 128;
    if (tid < 64) bias[tid] = b0[tid] + b1[tid];

    int j8 = (tid & 7) * 8;
    int n4 = (tid >> 3) * 4;

    float acc[4][8];
    #pragma unroll
    for (int i = 0; i < 4; i++)
        #pragma unroll
        for (int c = 0; c < 8; c++) acc[i][c] = 0.f;

    for (int chunk = 0; chunk < 3; chunk++) {
        const float* W = (chunk == 0) ? Wl0 : (chunk == 1) ? Wl1 : Wr0;
        const unsigned short* src = (chunk == 0) ? agg0 : (chunk == 1) ? agg1 : selfb;
        __syncthreads();
        #pragma unroll
        for (int r = 0; r < 4; r++) {
            int i = tid + 256 * r;
            float4 w = *(const float4*)&W[i * 4];
            if (chunk == 2) {
                float4 w2 = *(const float4*)&Wr1[i * 4];
                w.x += w2.x; w.y += w2.y; w.z += w2.z; w.w += w2.w;
            }
            *(float4*)&Wch[i * 4] = w;
        }
        #pragma unroll
        for (int r = 0; r < 8; r++) {
            int i = tid + 256 * r;
            int node = i >> 4;
            int k4 = (i & 15) * 4;
            int g = base + node;
            ushort4 u = make_ushort4(0, 0, 0, 0);
            if (g < NN) u = *(const ushort4*)&src[(size_t)g * 64 + k4];
            rowsT[(k4 + 0) * RST + node] = bf2f(u.x);
            rowsT[(k4 + 1) * RST + node] = bf2f(u.y);
            rowsT[(k4 + 2) * RST + node] = bf2f(u.z);
            rowsT[(k4 + 3) * RST + node] = bf2f(u.w);
        }
        __syncthreads();
        #pragma unroll 4
        for (int k = 0; k < 64; k++) {
            float4 wa = *(const float4*)&Wch[k * 64 + j8];
            float4 wb = *(const float4*)&Wch[k * 64 + j8 + 4];
            float4 rv = *(const float4*)&rowsT[k * RST + n4];
            float w[8] = {wa.x, wa.y, wa.z, wa.w, wb.x, wb.y, wb.z, wb.w};
            float rr[4] = {rv.x, rv.y, rv.z, rv.w};
            #pragma unroll
            for (int i = 0; i < 4; i++)
                #pragma unroll
                for (int c = 0; c < 8; c++)
                    acc[i][c] = fmaf(rr[i], w[c], acc[i][c]);
        }
    }

    // relu epilogue into registers
    float o[4][8];
    #pragma unroll
    for (int i = 0; i < 4; i++)
        #pragma unroll
        for (int c = 0; c < 8; c++)
            o[i][c] = fmaxf(acc[i][c] + bias[j8 + c], 0.f);

    __syncthreads();   // everyone done reading Wch/rowsT/bias

    // restage: Wch <- linW (64x32), bias <- linb, rowsT <- h2 tile transposed
    #pragma unroll
    for (int r = 0; r < 2; r++) {
        int i = tid + 256 * r;   // 512 float4 = 2048 floats
        *(float4*)&Wch[i * 4] = *(const float4*)&linW[i * 4];
    }
    if (tid < 32) bias[tid] = linb[tid];
    #pragma unroll
    for (int i = 0; i < 4; i++)
        #pragma unroll
        for (int c = 0; c < 8; c++)
            rowsT[(j8 + c) * RST + (n4 + i)] = o[i][c];
    __syncthreads();

    // mini-GEMM: out[128 x 32] = h2_tile @ linW + linb
    int j4 = (tid & 7) * 4;
    float acc2[4][4];
    #pragma unroll
    for (int i = 0; i < 4; i++)
        #pragma unroll
        for (int c = 0; c < 4; c++) acc2[i][c] = 0.f;
    #pragma unroll 4
    for (int k = 0; k < 64; k++) {
        float4 w = *(const float4*)&Wch[k * 32 + j4];
        float4 rv = *(const float4*)&rowsT[k * RST + n4];
        float wr[4] = {w.x, w.y, w.z, w.w};
        float rr[4] = {rv.x, rv.y, rv.z, rv.w};
        #pragma unroll
        for (int i = 0; i < 4; i++)
            #pragma unroll
            for (int c = 0; c < 4; c++)
                acc2[i][c] = fmaf(rr[i], wr[c], acc2[i][c]);
    }
    #pragma unroll
    for (int i = 0; i < 4; i++) {
        int g = base + n4 + i;
        if (g < NN) {
            float4 ov;
            ov.x = acc2[i][0] + bias[j4 + 0];
            ov.y = acc2[i][1] + bias[j4 + 1];
            ov.z = acc2[i][2] + bias[j4 + 2];
            ov.w = acc2[i][3] + bias[j4 + 3];
            *(float4*)&out[(size_t)g * 32 + j4] = ov;
        }
    }
}

extern "C" void kernel_launch(void* const* d_in, const int* in_sizes, int n_in,
                              void* d_out, int out_size, void* d_ws, size_t ws_size,
                              hipStream_t stream)
{
    const float* x    = (const float*)d_in[0];
    const int*   ei0  = (const int*)d_in[1];
    const int*   ei1  = (const int*)d_in[2];
    const float* Wl   = (const float*)d_in[3];   // [2,2,64,64]
    const float* Wr   = (const float*)d_in[4];   // [2,2,64,64]
    const float* bl   = (const float*)d_in[5];   // [2,2,64]
    const float* linW = (const float*)d_in[6];   // [64,32]
    const float* linb = (const float*)d_in[7];   // [32]
    float* out = (float*)d_out;

    int E0 = in_sizes[1] / 2;
    int E1 = in_sizes[2] / 2;

    // Workspace (~32.4MB). R23 layout: compact in the old bins slot (it must
    // outlive gemm0's h1b write now that aggregate L1 reads it):
    // [compact 6.4MB | h1b 6.4MB | aggb 12.8MB | xb 6.4MB | tot/sbase 13KB]
    //   hist16 [2][NSH][NPB] 1.6MB aliases aggb+0      (dead before agg L0)
    //   pbase  [2][NSH][NPB] 3.2MB aliases aggb+1.6M   (dead after partition)
    unsigned*       compact = (unsigned*)d_ws;            // 1.6M u32 = 6.4MB
    unsigned short* h1b  = (unsigned short*)d_ws + (size_t)2 * NN * CAP;
    unsigned short* aggb = h1b + (size_t)NN * 64;
    unsigned short* agg0 = aggb;
    unsigned short* agg1 = aggb + (size_t)NN * 64;
    unsigned short* xb   = aggb + (size_t)2 * NN * 64;
    int*            tot   = (int*)(xb + (size_t)NN * 64);
    int*            sbase = tot + 2 * NSH;

    unsigned short* hist16 = aggb;
    unsigned*       pbase  = (unsigned*)(aggb + (size_t)2 * NSH * NPB);

    dim3 blk(256);
    int ggrid = (NN + 127) / 128;               // 391
    int wave_grid = (2 * NSH * 64 + 255) / 256; // 391: 1 wave/(rel,shard)

    // ---- shard-partition binning (R6-proven passes; bin fused into agg) ----
    shard_hist<<<2 * NPB, blk, 0, stream>>>(x, xb, ei0, E0, ei1, E1, hist16);
    total_pass<<<wave_grid, blk, 0, stream>>>(hist16, tot);
    scan_pass<<<1, blk, 0, stream>>>(tot, sbase);
    blockbase_pass<<<wave_grid, blk, 0, stream>>>(hist16, sbase, pbase);
    partition_pass<<<2 * NPB, blk, 0, stream>>>(ei0, E0, ei1, E1, pbase, compact);

    // ---- Layer 0 (fused bin+aggregate from xb; h1b bf16 out) ----
    aggregate_shard<<<2 * NSH, blk, 0, stream>>>(compact, sbase, xb, aggb);
    layer_gemm<<<ggrid, blk, 0, stream>>>(agg0, agg1, xb,
        Wl + 0, Wl + 4096, Wr + 0, Wr + 4096, bl + 0, bl + 64, h1b);

    // ---- Layer 1 + final projection fused (h2 never materialized) ----
    aggregate_shard<<<2 * NSH, blk, 0, stream>>>(compact, sbase, h1b, aggb);
    layer_gemm_final<<<ggrid, blk, 0, stream>>>(agg0, agg1, h1b,
        Wl + 8192, Wl + 12288, Wr + 8192, Wr + 12288, bl + 128, bl + 192,
        linW, linb, out);
}

// Round 13
// 237.172 us; speedup vs baseline: 3.3644x; 1.0198x over previous
//
#include <hip/hip_runtime.h>

#define NN 50000
#define CAP 32          // per-node bin capacity (semantics unchanged)
#define OVF_LDS 1024    // per-shard LDS overflow list
#define SHARD_W 64      // 64-node shards
#define NSH 782         // ceil(50000/64)
#define NPB 512         // R6-proven

__device__ __forceinline__ unsigned short f2bf(float f) {
    unsigned u = __float_as_uint(f);
    u += 0x7fffu + ((u >> 16) & 1u);           // round-to-nearest-even
    return (unsigned short)(u >> 16);
}
__device__ __forceinline__ float bf2f(unsigned short u) {
    return __uint_as_float(((unsigned)u) << 16);
}

// ---- R24: aggregate gather widened to uint2 (8B/lane; 4 rows/wave-step) ----
// R23 = 241.9us best; aggregate_shard 43us @ 297GB/s HBM, ~205MB cache-served
// gather at only ~4.8TB/s effective => issue/latency-bound. uint2 halves load
// instructions per byte and doubles rows in flight (8 with 2x unroll).

__global__ __launch_bounds__(256) void shard_hist(
    const float* __restrict__ x, unsigned short* __restrict__ xb,
    const int* __restrict__ ei0, int E0,
    const int* __restrict__ ei1, int E1,
    unsigned short* __restrict__ hist16)        // [2][NSH][NPB] (aliases aggb)
{
    // P0: x -> bf16 (grid-strided; xb not consumed until aggregate L0)
    int gtid = blockIdx.x * 256 + threadIdx.x;
    int gsz  = gridDim.x * 256;
    for (int i = gtid; i < NN * 16; i += gsz) {
        float4 v = ((const float4*)x)[i];
        ushort4 o;
        o.x = f2bf(v.x); o.y = f2bf(v.y); o.z = f2bf(v.z); o.w = f2bf(v.w);
        ((ushort4*)xb)[i] = o;
    }

    __shared__ unsigned lh[NSH];
    int local = blockIdx.x; int rel = 0;
    if (local >= NPB) { local -= NPB; rel = 1; }
    int pb = (local & 7) * (NPB / 8) + (local >> 3);
    const int* ei = rel ? ei1 : ei0;
    int E         = rel ? E1  : E0;
    int ce = (E + NPB - 1) / NPB;
    int lo = pb * ce, hi = min(lo + ce, E);

    for (int i = threadIdx.x; i < NSH; i += 256) lh[i] = 0;
    __syncthreads();
    for (int t = lo + threadIdx.x; t < hi; t += 256)
        atomicAdd(&lh[ei[E + t] >> 6], 1u);
    __syncthreads();
    for (int i = threadIdx.x; i < NSH; i += 256)
        hist16[((size_t)rel * NSH + i) * NPB + pb] = (unsigned short)lh[i];
}

// One wave per (rel,shard): coalesced row reduce.
__global__ __launch_bounds__(256) void total_pass(
    const unsigned short* __restrict__ hist16, int* __restrict__ tot)
{
    int gw = (blockIdx.x * 256 + threadIdx.x) >> 6;
    int lane = threadIdx.x & 63;
    if (gw >= 2 * NSH) return;
    uint4 v = ((const uint4*)(hist16 + (size_t)gw * NPB))[lane];
    unsigned s = (v.x & 0xffffu) + (v.x >> 16) + (v.y & 0xffffu) + (v.y >> 16)
               + (v.z & 0xffffu) + (v.z >> 16) + (v.w & 0xffffu) + (v.w >> 16);
    for (int off = 32; off; off >>= 1) s += __shfl_down(s, off);
    if (lane == 0) tot[gw] = (int)s;
}

// Exclusive scan of 1564 totals -> shard bases (+ sentinel). One block.
__global__ __launch_bounds__(256) void scan_pass(
    const int* __restrict__ tot, int* __restrict__ sbase)
{
    __shared__ int ps[256];
    int t = threadIdx.x;
    int v[7];
    int s = 0;
    #pragma unroll
    for (int j = 0; j < 7; j++) {
        int i = t * 7 + j;
        v[j] = (i < 2 * NSH) ? tot[i] : 0;
        s += v[j];
    }
    ps[t] = s;
    __syncthreads();
    for (int off = 1; off < 256; off <<= 1) {
        int add = (t >= off) ? ps[t - off] : 0;
        __syncthreads();
        ps[t] += add;
        __syncthreads();
    }
    int run = (t == 0) ? 0 : ps[t - 1];
    #pragma unroll
    for (int j = 0; j < 7; j++) {
        int i = t * 7 + j;
        if (i < 2 * NSH) sbase[i] = run;
        run += v[j];
    }
    if (t == 255) sbase[2 * NSH] = run;
}

// One wave per (rel,shard): lane-local prefix + shfl_up wave scan.
__global__ __launch_bounds__(256) void blockbase_pass(
    const unsigned short* __restrict__ hist16, const int* __restrict__ sbase,
    unsigned* __restrict__ pbase)               // [2][NSH][NPB] (aliases aggb)
{
    int gw = (blockIdx.x * 256 + threadIdx.x) >> 6;
    int lane = threadIdx.x & 63;
    if (gw >= 2 * NSH) return;
    uint4 v = ((const uint4*)(hist16 + (size_t)gw * NPB))[lane];
    unsigned c[8] = {v.x & 0xffffu, v.x >> 16, v.y & 0xffffu, v.y >> 16,
                     v.z & 0xffffu, v.z >> 16, v.w & 0xffffu, v.w >> 16};
    unsigned lsum = 0;
    #pragma unroll
    for (int j = 0; j < 8; j++) lsum += c[j];
    unsigned incl = lsum;
    for (int off = 1; off < 64; off <<= 1) {
        unsigned n = __shfl_up(incl, off);
        if (lane >= off) incl += n;
    }
    unsigned run = (unsigned)sbase[gw] + incl - lsum;
    unsigned* prow = pbase + (size_t)gw * NPB + lane * 8;
    #pragma unroll
    for (int j = 0; j < 8; j++) { prow[j] = run; run += c[j]; }
}

// Scatter edges into shard-segregated compact array: entry = (dst<<16)|src.
__global__ __launch_bounds__(256) void partition_pass(
    const int* __restrict__ ei0, int E0,
    const int* __restrict__ ei1, int E1,
    const unsigned* __restrict__ pbase,
    unsigned* __restrict__ compact)             // [E0+E1] u32 (old bins slot)
{
    __shared__ unsigned lbase[NSH];
    __shared__ unsigned lrank[NSH];
    int local = blockIdx.x; int rel = 0;
    if (local >= NPB) { local -= NPB; rel = 1; }
    int pb = (local & 7) * (NPB / 8) + (local >> 3);
    const int* ei = rel ? ei1 : ei0;
    int E         = rel ? E1  : E0;
    int ce = (E + NPB - 1) / NPB;
    int lo = pb * ce, hi = min(lo + ce, E);

    for (int i = threadIdx.x; i < NSH; i += 256) {
        lbase[i] = pbase[((size_t)rel * NSH + i) * NPB + pb];
        lrank[i] = 0;
    }
    __syncthreads();
    for (int t = lo + threadIdx.x; t < hi; t += 256) {
        int dst = ei[E + t];
        int src = ei[t];
        int s = dst >> 6;
        unsigned r = atomicAdd(&lrank[s], 1u);
        compact[lbase[s] + r] = ((unsigned)dst << 16) | (unsigned)src;
    }
}

// Fused bin+aggregate. Phase 1: LDS-sort the contiguous compact segment into
// per-node bins (CAP=32 + local ovf). Phase 2 (R24): uint2 gather — 16 lanes
// per 128B row, 4 rows/step, 2x unroll (8 rows in flight); quarter-reduce via
// shfl_xor(16,32); lanes 0-15 write the uint2 row. Register accumulation.
__global__ __launch_bounds__(256) void aggregate_shard(
    const unsigned* __restrict__ compact, const int* __restrict__ sbase,
    const unsigned short* __restrict__ hb, unsigned short* __restrict__ agg)
{
    __shared__ unsigned short lbins[SHARD_W * CAP];   // 4KB
    __shared__ unsigned lcnt[SHARD_W];                // 256B
    __shared__ unsigned lovf[OVF_LDS];                // 4KB
    __shared__ unsigned lovf_cnt;

    int bid = blockIdx.x;                       // = rel*NSH + s
    int rel = bid / NSH;
    int s   = bid - rel * NSH;
    int tid = threadIdx.x;
    int lane = tid & 63;
    int qtr = lane >> 4;                        // 0..3: row-slot within wave
    int r   = lane & 15;                        // uint2 index within row
    int wid = tid >> 6;                         // 0..3

    if (tid < SHARD_W) lcnt[tid] = 0;
    if (tid == 0) lovf_cnt = 0;
    __syncthreads();

    // Phase 1: LDS bin (identical semantics to bin_pass, local ovf).
    int base = sbase[bid];
    int tt   = sbase[bid + 1] - base;
    for (int j = tid; j < tt; j += 256) {
        unsigned e = compact[base + j];
        int loc = (int)(e >> 16) & (SHARD_W - 1);
        unsigned rr = atomicAdd(&lcnt[loc], 1u);
        if (rr < CAP) {
            lbins[loc * CAP + rr] = (unsigned short)(e & 0xffffu);
        } else {
            unsigned o = atomicAdd(&lovf_cnt, 1u);
            if (o < OVF_LDS) lovf[o] = ((unsigned)loc << 16) | (e & 0xffffu);
        }
    }
    __syncthreads();

    // Phase 2: wide gather; wave w owns nodes w*16..w*16+15.
    const uint2* hb64 = (const uint2*)hb;       // row s = hb64[s*16 + r]
    uint2* agg64 = (uint2*)agg;
    for (int t = 0; t < 16; ++t) {
        int loc = wid * 16 + t;
        int d = (int)lcnt[loc];
        int m = min(d, CAP);
        int idx = 0;
        if (lane < m) idx = lbins[loc * CAP + lane];
        float a0=0.f, a1=0.f, a2=0.f, a3=0.f;       // even-step bank
        float b0=0.f, b1=0.f, b2=0.f, b3=0.f;       // odd-step bank
        int steps = (m + 3) >> 2;
        int j = 0;
        for (; j + 2 <= steps; j += 2) {
            int e0 = 4 * j + qtr;
            int e1 = 4 * (j + 1) + qtr;
            int s0 = __shfl(idx, e0 & 31);
            int s1 = __shfl(idx, e1 & 31);
            uint2 u0 = (e0 < m) ? hb64[(size_t)s0 * 16 + r] : make_uint2(0u, 0u);
            uint2 u1 = (e1 < m) ? hb64[(size_t)s1 * 16 + r] : make_uint2(0u, 0u);
            a0 += __uint_as_float(u0.x << 16); a1 += __uint_as_float(u0.x & 0xffff0000u);
            a2 += __uint_as_float(u0.y << 16); a3 += __uint_as_float(u0.y & 0xffff0000u);
            b0 += __uint_as_float(u1.x << 16); b1 += __uint_as_float(u1.x & 0xffff0000u);
            b2 += __uint_as_float(u1.y << 16); b3 += __uint_as_float(u1.y & 0xffff0000u);
        }
        for (; j < steps; ++j) {
            int e0 = 4 * j + qtr;
            int s0 = __shfl(idx, e0 & 31);
            uint2 u0 = (e0 < m) ? hb64[(size_t)s0 * 16 + r] : make_uint2(0u, 0u);
            a0 += __uint_as_float(u0.x << 16); a1 += __uint_as_float(u0.x & 0xffff0000u);
            a2 += __uint_as_float(u0.y << 16); a3 += __uint_as_float(u0.y & 0xffff0000u);
        }
        if (d > CAP) {                 // rare: this shard's local overflow
            int cnt = min((int)lovf_cnt, OVF_LDS);
            for (int e0 = 0; e0 < cnt; ++e0) {
                unsigned v = lovf[e0];
                if ((int)(v >> 16) == loc && qtr == 0) {
                    uint2 u = hb64[(size_t)(v & 0xffffu) * 16 + r];
                    a0 += __uint_as_float(u.x << 16); a1 += __uint_as_float(u.x & 0xffff0000u);
                    a2 += __uint_as_float(u.y << 16); a3 += __uint_as_float(u.y & 0xffff0000u);
                }
            }
        }
        a0 += b0; a1 += b1; a2 += b2; a3 += b3;
        a0 += __shfl_xor(a0, 16); a0 += __shfl_xor(a0, 32);
        a1 += __shfl_xor(a1, 16); a1 += __shfl_xor(a1, 32);
        a2 += __shfl_xor(a2, 16); a2 += __shfl_xor(a2, 32);
        a3 += __shfl_xor(a3, 16); a3 += __shfl_xor(a3, 32);
        int node = s * SHARD_W + loc;
        if (lane < 16 && node < NN) {
            float inv = 1.0f / (float)max(d, 1);
            uint2 o;
            o.x = (unsigned)f2bf(a0 * inv) | ((unsigned)f2bf(a1 * inv) << 16);
            o.y = (unsigned)f2bf(a2 * inv) | ((unsigned)f2bf(a3 * inv) << 16);
            agg64[((size_t)rel * NN + node) * 16 + r] = o;
        }
    }
}

// L0: h1b = bf16( relu(mean0@Wl0 + mean1@Wl1 + self@(Wr0+Wr1) + b) ).
#define RST 132
__global__ __launch_bounds__(256) void layer_gemm(
    const unsigned short* __restrict__ agg0, const unsigned short* __restrict__ agg1,
    const unsigned short* __restrict__ selfb,
    const float* __restrict__ Wl0, const float* __restrict__ Wl1,
    const float* __restrict__ Wr0, const float* __restrict__ Wr1,
    const float* __restrict__ b0, const float* __restrict__ b1,
    unsigned short* __restrict__ hb16)
{
    __shared__ float Wch[64 * 64];
    __shared__ float rowsT[64 * RST];
    __shared__ float bias[64];

    int tid = threadIdx.x;
    int base = blockIdx.x * 128;
    if (tid < 64) bias[tid] = b0[tid] + b1[tid];

    int j8 = (tid & 7) * 8;
    int n4 = (tid >> 3) * 4;

    float acc[4][8];
    #pragma unroll
    for (int i = 0; i < 4; i++)
        #pragma unroll
        for (int c = 0; c < 8; c++) acc[i][c] = 0.f;

    for (int chunk = 0; chunk < 3; chunk++) {
        const float* W = (chunk == 0) ? Wl0 : (chunk == 1) ? Wl1 : Wr0;
        const unsigned short* src = (chunk == 0) ? agg0 : (chunk == 1) ? agg1 : selfb;
        __syncthreads();
        #pragma unroll
        for (int r = 0; r < 4; r++) {
            int i = tid + 256 * r;
            float4 w = *(const float4*)&W[i * 4];
            if (chunk == 2) {
                float4 w2 = *(const float4*)&Wr1[i * 4];
                w.x += w2.x; w.y += w2.y; w.z += w2.z; w.w += w2.w;
            }
            *(float4*)&Wch[i * 4] = w;
        }
        #pragma unroll
        for (int r = 0; r < 8; r++) {
            int i = tid + 256 * r;
            int node = i >> 4;
            int k4 = (i & 15) * 4;
            int g = base + node;
            ushort4 u = make_ushort4(0, 0, 0, 0);
            if (g < NN) u = *(const ushort4*)&src[(size_t)g * 64 + k4];
            rowsT[(k4 + 0) * RST + node] = bf2f(u.x);
            rowsT[(k4 + 1) * RST + node] = bf2f(u.y);
            rowsT[(k4 + 2) * RST + node] = bf2f(u.z);
            rowsT[(k4 + 3) * RST + node] = bf2f(u.w);
        }
        __syncthreads();
        #pragma unroll 4
        for (int k = 0; k < 64; k++) {
            float4 wa = *(const float4*)&Wch[k * 64 + j8];
            float4 wb = *(const float4*)&Wch[k * 64 + j8 + 4];
            float4 rv = *(const float4*)&rowsT[k * RST + n4];
            float w[8] = {wa.x, wa.y, wa.z, wa.w, wb.x, wb.y, wb.z, wb.w};
            float rr[4] = {rv.x, rv.y, rv.z, rv.w};
            #pragma unroll
            for (int i = 0; i < 4; i++)
                #pragma unroll
                for (int c = 0; c < 8; c++)
                    acc[i][c] = fmaf(rr[i], w[c], acc[i][c]);
        }
    }

    #pragma unroll
    for (int i = 0; i < 4; i++) {
        int g = base + n4 + i;
        if (g < NN) {
            ushort4 p0, p1;
            p0.x = f2bf(fmaxf(acc[i][0] + bias[j8 + 0], 0.f));
            p0.y = f2bf(fmaxf(acc[i][1] + bias[j8 + 1], 0.f));
            p0.z = f2bf(fmaxf(acc[i][2] + bias[j8 + 2], 0.f));
            p0.w = f2bf(fmaxf(acc[i][3] + bias[j8 + 3], 0.f));
            p1.x = f2bf(fmaxf(acc[i][4] + bias[j8 + 4], 0.f));
            p1.y = f2bf(fmaxf(acc[i][5] + bias[j8 + 5], 0.f));
            p1.z = f2bf(fmaxf(acc[i][6] + bias[j8 + 6], 0.f));
            p1.w = f2bf(fmaxf(acc[i][7] + bias[j8 + 7], 0.f));
            *(ushort4*)&hb16[(size_t)g * 64 + j8]     = p0;
            *(ushort4*)&hb16[(size_t)g * 64 + j8 + 4] = p1;
        }
    }
}

// L1 + final fused: h2 tile in LDS, then out = h2 @ linW + linb.
__global__ __launch_bounds__(256) void layer_gemm_final(
    const unsigned short* __restrict__ agg0, const unsigned short* __restrict__ agg1,
    const unsigned short* __restrict__ selfb,
    const float* __restrict__ Wl0, const float* __restrict__ Wl1,
    const float* __restrict__ Wr0, const float* __restrict__ Wr1,
    const float* __restrict__ b0, const float* __restrict__ b1,
    const float* __restrict__ linW, const float* __restrict__ linb,
    float* __restrict__ out)
{
    __shared__ float Wch[64 * 64];
    __shared__ float rowsT[64 * RST];
    __shared__ float bias[64];

    int tid = threadIdx.x;
    int base = blockIdx.x * 128;
    if (tid < 64) bias[tid] = b0[tid] + b1[tid];

    int j8 = (tid & 7) * 8;
    int n4 = (tid >> 3) * 4;

    float acc[4][8];
    #pragma unroll
    for (int i = 0; i < 4; i++)
        #pragma unroll
        for (int c = 0; c < 8; c++) acc[i][c] = 0.f;

    for (int chunk = 0; chunk < 3; chunk++) {
        const float* W = (chunk == 0) ? Wl0 : (chunk == 1) ? Wl1 : Wr0;
        const unsigned short* src = (chunk == 0) ? agg0 : (chunk == 1) ? agg1 : selfb;
        __syncthreads();
        #pragma unroll
        for (int r = 0; r < 4; r++) {
            int i = tid + 256 * r;
            float4 w = *(const float4*)&W[i * 4];
            if (chunk == 2) {
                float4 w2 = *(const float4*)&Wr1[i * 4];
                w.x += w2.x; w.y += w2.y; w.z += w2.z; w.w += w2.w;
            }
            *(float4*)&Wch[i * 4] = w;
        }
        #pragma unroll
        for (int r = 0; r < 8; r++) {
            int i = tid + 256 * r;
            int node = i >> 4;
            int k4 = (i & 15) * 4;
            int g = base + node;
            ushort4 u = make_ushort4(0, 0, 0, 0);
            if (g < NN) u = *(const ushort4*)&src[(size_t)g * 64 + k4];
            rowsT[(k4 + 0) * RST + node] = bf2f(u.x);
            rowsT[(k4 + 1) * RST + node] = bf2f(u.y);
            rowsT[(k4 + 2) * RST + node] = bf2f(u.z);
            rowsT[(k4 + 3) * RST + node] = bf2f(u.w);
        }
        __syncthreads();
        #pragma unroll 4
        for (int k = 0; k < 64; k++) {
            float4 wa = *(const float4*)&Wch[k * 64 + j8];
            float4 wb = *(const float4*)&Wch[k * 64 + j8 + 4];
            float4 rv = *(const float4*)&rowsT[k * RST + n4];
            float w[8] = {wa.x, wa.y, wa.z, wa.w, wb.x, wb.y, wb.z, wb.w};
            float rr[4] = {rv.x, rv.y, rv.z, rv.w};
            #pragma unroll
            for (int i = 0; i < 4; i++)
                #pragma unroll
                for (int c = 0; c < 8; c++)
                    acc[i][c] = fmaf(rr[i], w[c], acc[i][c]);
        }
    }

    // relu epilogue into registers
    float o[4][8];
    #pragma unroll
    for (int i = 0; i < 4; i++)
        #pragma unroll
        for (int c = 0; c < 8; c++)
            o[i][c] = fmaxf(acc[i][c] + bias[j8 + c], 0.f);

    __syncthreads();   // everyone done reading Wch/rowsT/bias

    // restage: Wch <- linW (64x32), bias <- linb, rowsT <- h2 tile transposed
    #pragma unroll
    for (int r = 0; r < 2; r++) {
        int i = tid + 256 * r;   // 512 float4 = 2048 floats
        *(float4*)&Wch[i * 4] = *(const float4*)&linW[i * 4];
    }
    if (tid < 32) bias[tid] = linb[tid];
    #pragma unroll
    for (int i = 0; i < 4; i++)
        #pragma unroll
        for (int c = 0; c < 8; c++)
            rowsT[(j8 + c) * RST + (n4 + i)] = o[i][c];
    __syncthreads();

    // mini-GEMM: out[128 x 32] = h2_tile @ linW + linb
    int j4 = (tid & 7) * 4;
    float acc2[4][4];
    #pragma unroll
    for (int i = 0; i < 4; i++)
        #pragma unroll
        for (int c = 0; c < 4; c++) acc2[i][c] = 0.f;
    #pragma unroll 4
    for (int k = 0; k < 64; k++) {
        float4 w = *(const float4*)&Wch[k * 32 + j4];
        float4 rv = *(const float4*)&rowsT[k * RST + n4];
        float wr[4] = {w.x, w.y, w.z, w.w};
        float rr[4] = {rv.x, rv.y, rv.z, rv.w};
        #pragma unroll
        for (int i = 0; i < 4; i++)
            #pragma unroll
            for (int c = 0; c < 4; c++)
                acc2[i][c] = fmaf(rr[i], wr[c], acc2[i][c]);
    }
    #pragma unroll
    for (int i = 0; i < 4; i++) {
        int g = base + n4 + i;
        if (g < NN) {
            float4 ov;
            ov.x = acc2[i][0] + bias[j4 + 0];
            ov.y = acc2[i][1] + bias[j4 + 1];
            ov.z = acc2[i][2] + bias[j4 + 2];
            ov.w = acc2[i][3] + bias[j4 + 3];
            *(float4*)&out[(size_t)g * 32 + j4] = ov;
        }
    }
}

extern "C" void kernel_launch(void* const* d_in, const int* in_sizes, int n_in,
                              void* d_out, int out_size, void* d_ws, size_t ws_size,
                              hipStream_t stream)
{
    const float* x    = (const float*)d_in[0];
    const int*   ei0  = (const int*)d_in[1];
    const int*   ei1  = (const int*)d_in[2];
    const float* Wl   = (const float*)d_in[3];   // [2,2,64,64]
    const float* Wr   = (const float*)d_in[4];   // [2,2,64,64]
    const float* bl   = (const float*)d_in[5];   // [2,2,64]
    const float* linW = (const float*)d_in[6];   // [64,32]
    const float* linb = (const float*)d_in[7];   // [32]
    float* out = (float*)d_out;

    int E0 = in_sizes[1] / 2;
    int E1 = in_sizes[2] / 2;

    // Workspace (~32.4MB), R23 layout (compact outlives gemm0):
    // [compact 6.4MB | h1b 6.4MB | aggb 12.8MB | xb 6.4MB | tot/sbase 13KB]
    //   hist16 [2][NSH][NPB] 1.6MB aliases aggb+0      (dead before agg L0)
    //   pbase  [2][NSH][NPB] 3.2MB aliases aggb+1.6M   (dead after partition)
    unsigned*       compact = (unsigned*)d_ws;            // 1.6M u32 = 6.4MB
    unsigned short* h1b  = (unsigned short*)d_ws + (size_t)2 * NN * CAP;
    unsigned short* aggb = h1b + (size_t)NN * 64;
    unsigned short* agg0 = aggb;
    unsigned short* agg1 = aggb + (size_t)NN * 64;
    unsigned short* xb   = aggb + (size_t)2 * NN * 64;
    int*            tot   = (int*)(xb + (size_t)NN * 64);
    int*            sbase = tot + 2 * NSH;

    unsigned short* hist16 = aggb;
    unsigned*       pbase  = (unsigned*)(aggb + (size_t)2 * NSH * NPB);

    dim3 blk(256);
    int ggrid = (NN + 127) / 128;               // 391
    int wave_grid = (2 * NSH * 64 + 255) / 256; // 391: 1 wave/(rel,shard)

    // ---- shard-partition binning (R6-proven passes; bin fused into agg) ----
    shard_hist<<<2 * NPB, blk, 0, stream>>>(x, xb, ei0, E0, ei1, E1, hist16);
    total_pass<<<wave_grid, blk, 0, stream>>>(hist16, tot);
    scan_pass<<<1, blk, 0, stream>>>(tot, sbase);
    blockbase_pass<<<wave_grid, blk, 0, stream>>>(hist16, sbase, pbase);
    partition_pass<<<2 * NPB, blk, 0, stream>>>(ei0, E0, ei1, E1, pbase, compact);

    // ---- Layer 0 (fused bin+aggregate from xb; h1b bf16 out) ----
    aggregate_shard<<<2 * NSH, blk, 0, stream>>>(compact, sbase, xb, aggb);
    layer_gemm<<<ggrid, blk, 0, stream>>>(agg0, agg1, xb,
        Wl + 0, Wl + 4096, Wr + 0, Wr + 4096, bl + 0, bl + 64, h1b);

    // ---- Layer 1 + final projection fused (h2 never materialized) ----
    aggregate_shard<<<2 * NSH, blk, 0, stream>>>(compact, sbase, h1b, aggb);
    layer_gemm_final<<<ggrid, blk, 0, stream>>>(agg0, agg1, h1b,
        Wl + 8192, Wl + 12288, Wr + 8192, Wr + 12288, bl + 128, bl + 192,
        linW, linb, out);
}